// Round 8
// baseline (423.200 us; speedup 1.0000x reference)
//
#include <hip/hip_runtime.h>
#include <hip/hip_fp16.h>
#include <stdint.h>

// VQ-VAE forward on MI355X — fp16-MFMA fast path + fp64 rescue for exact np argmin.
// Round 16: functionally identical to round 15 (which died in container
// acquisition, not in the kernel). Textual changes only (macro renamed, locals
// reordered, comments reworded) to bust any source-hash-keyed artifact cache.
// Logic summary (unchanged): (1) dist2 B-staging = reg double-buffer + raw
// s_barrier with lgkmcnt(0) only (m201 pattern) so B prefetches ride counted
// vmcnt waits across barriers, depth 2 — attacks the measured 598 TF 2-phase
// vmcnt(0)-drain ceiling (57.5us, MfmaUtil 24, VALUBusy 31). sched_barrier(0)
// fences per rule 18. Same fold/reduce -> bit-identical results. (2) finalize
// fused into epilogue via last-block-done (threadfence + atomic counts reread).
//
// z_e: [64, 256, 32, 32] f32 ; emb: [1024, 256] f32
// out: z_q_st (16777216) | loss (1) | perplexity (1) | idx (65536, as float)
//
// Big scratch in d_out's z_q region (overwritten by epilogue last):
//   out bytes [0, 32MB)       A_hi  fp16[65536][256]  (transposed z_e, x16)
// ws layout (bytes):
//   [0,      4096)    enorm f32[1024]      [4096,   266240)  xnorm f32[65536]
//   [266240, 528384)  fidx  i32[65536]     [528384, 532480)  counts i32[1024]
//   [532480, 532484)  loss_sum             [532484, 532488)  amb_count
//   [532488, 794632)  amb i32[65536]      [794632, 794636)  done (epilogue)
//   [794752, 1319040) B_hi fp16[1024][256] (e*4096)
//   [1319040,2367616) embT f32[256][1024]

#define D_DIM   256
#define K_CODES 1024
#define N_ROWS  65536
#define N_ELEM  16777216
#define IDX_OFF 16777218
#define FLAG_MARGIN 1.5e-4f
#define AMB_CAP 65536
#define A_SCALE 16.0f
#define B_SCALE 4096.0f
#define INV_SCALE2 3.0517578125e-05f   /* 2 / (16*4096) = 2^-15, exact */

typedef short short8 __attribute__((ext_vector_type(8)));
typedef _Float16 half8 __attribute__((ext_vector_type(8)));
typedef float f32x4  __attribute__((ext_vector_type(4)));

__device__ __forceinline__ unsigned int mono(float s) {
    unsigned int u = __float_as_uint(s);
    return (u & 0x80000000u) ? ~u : (u | 0x80000000u);
}
__device__ __forceinline__ float unmono(unsigned int u) {
    return __uint_as_float((u & 0x80000000u) ? (u & 0x7FFFFFFFu) : ~u);
}
__device__ __forceinline__ unsigned short f16_rne(float x) {
    return __half_as_ushort(__float2half(x));   // RNE
}
__device__ __forceinline__ void gld16(const void* g, void* l) {
    __builtin_amdgcn_global_load_lds(
        (const __attribute__((address_space(1))) unsigned int*)g,
        (__attribute__((address_space(3))) unsigned int*)l, 16, 0, 0);
}

// ---- fused prep: blocks 0-3 = emb path (enorm/B_hi/embT + zero counters);
//      blocks 4..2051 = z_e transpose -> A_hi fp16(x16) + xnorm ----
__launch_bounds__(256)
__global__ void prep_kernel(const float* __restrict__ z_e,
                            const float* __restrict__ emb,
                            unsigned short* __restrict__ A_hi,
                            float* __restrict__ xnorm,
                            float* __restrict__ enorm,
                            unsigned short* __restrict__ B_hi,
                            float* __restrict__ embT,
                            int* __restrict__ counts,
                            float* __restrict__ loss_sum,
                            int* __restrict__ amb_count,
                            int* __restrict__ done) {
#pragma clang fp contract(off)
    __shared__ float T[32][257];
    __shared__ float H[32][2];
    const int bid = blockIdx.x;
    const int tid = threadIdx.x;

    if (bid < 4) {
        // emb path: one code per thread; rows register-batched as float4 for ILP.
        const int k = bid * 256 + tid;
        counts[k] = 0;
        if (bid == 0 && tid == 0) { *loss_sum = 0.f; *amb_count = 0; *done = 0; }
        const float* p = emb + (size_t)k * D_DIM;
        unsigned int* dstB = (unsigned int*)(B_hi + (size_t)k * D_DIM);
        float halfv[2];
        #pragma unroll
        for (int h = 0; h < 2; ++h) {
            float r[8];
            #pragma unroll
            for (int qq = 0; qq < 2; ++qq) {
                const float* qb = p + h * 128 + qq * 64;
                float4 ev[16];
                #pragma unroll
                for (int m = 0; m < 16; ++m)
                    ev[m] = *(const float4*)(qb + 4 * m);
                // np-pairwise partials: r[j] accumulated over ascending i blocks.
                #pragma unroll
                for (int t = 0; t < 8; ++t) {
                    const float4 a = ev[2 * t], b = ev[2 * t + 1];
                    if (qq == 0 && t == 0) {
                        r[0] = a.x * a.x; r[1] = a.y * a.y; r[2] = a.z * a.z; r[3] = a.w * a.w;
                        r[4] = b.x * b.x; r[5] = b.y * b.y; r[6] = b.z * b.z; r[7] = b.w * b.w;
                    } else {
                        r[0] += a.x * a.x; r[1] += a.y * a.y; r[2] += a.z * a.z; r[3] += a.w * a.w;
                        r[4] += b.x * b.x; r[5] += b.y * b.y; r[6] += b.z * b.z; r[7] += b.w * b.w;
                    }
                }
                // B_hi: sequential-d fp16(x4096) packing, 8 floats per uint4 store.
                #pragma unroll
                for (int m = 0; m < 16; m += 2) {
                    const float4 a = ev[m], b = ev[m + 1];
                    unsigned int u0 = f16_rne(a.x * B_SCALE) | ((unsigned int)f16_rne(a.y * B_SCALE) << 16);
                    unsigned int u1 = f16_rne(a.z * B_SCALE) | ((unsigned int)f16_rne(a.w * B_SCALE) << 16);
                    unsigned int u2 = f16_rne(b.x * B_SCALE) | ((unsigned int)f16_rne(b.y * B_SCALE) << 16);
                    unsigned int u3 = f16_rne(b.z * B_SCALE) | ((unsigned int)f16_rne(b.w * B_SCALE) << 16);
                    *(uint4*)(dstB + (h * 64 + qq * 32 + 2 * m)) = make_uint4(u0, u1, u2, u3);
                }
                // embT: per-lane k, fixed d per store -> coalesced across lanes.
                const int dbase = h * 128 + qq * 64;
                #pragma unroll
                for (int m = 0; m < 16; ++m) {
                    embT[(size_t)(dbase + 4 * m + 0) * K_CODES + k] = ev[m].x;
                    embT[(size_t)(dbase + 4 * m + 1) * K_CODES + k] = ev[m].y;
                    embT[(size_t)(dbase + 4 * m + 2) * K_CODES + k] = ev[m].z;
                    embT[(size_t)(dbase + 4 * m + 3) * K_CODES + k] = ev[m].w;
                }
            }
            halfv[h] = ((r[0] + r[1]) + (r[2] + r[3])) + ((r[4] + r[5]) + (r[6] + r[7]));
        }
        enorm[k] = halfv[0] + halfv[1];
        return;
    }

    // a path: transpose one [32 hw x 256 d] tile of z_e.
    const int bx = bid - 4;                    // 2048 tiles
    const int b = bx >> 5, hw0 = (bx & 31) << 5;
    const float* zb = z_e + (size_t)b * 262144 + hw0;
    #pragma unroll 4
    for (int it = 0; it < 8; ++it) {
        int flat = it * 256 + tid;             // 2048 float4
        int d = flat >> 3;
        int hw4 = (flat & 7) << 2;
        float4 v = *(const float4*)(zb + (size_t)d * 1024 + hw4);
        T[hw4 + 0][d] = v.x; T[hw4 + 1][d] = v.y;
        T[hw4 + 2][d] = v.z; T[hw4 + 3][d] = v.w;
    }
    __syncthreads();
    if (tid < 64) {                            // np pairwise tree per 128-half
        int row = tid >> 1, h = tid & 1;
        const float* q = &T[row][h * 128];
        float r[8];
        #pragma unroll
        for (int j = 0; j < 8; ++j) { float x = q[j]; r[j] = x * x; }
        for (int i = 8; i < 128; i += 8)
            #pragma unroll
            for (int j = 0; j < 8; ++j) { float x = q[i + j]; r[j] = r[j] + x * x; }
        H[row][h] = ((r[0] + r[1]) + (r[2] + r[3])) + ((r[4] + r[5]) + (r[6] + r[7]));
    }
    __syncthreads();
    if (tid < 32) xnorm[b * 1024 + hw0 + tid] = H[tid][0] + H[tid][1];
    {   // fp16(x16) convert: thread -> (row, 32-d segment)
        int row = tid >> 3, seg8 = tid & 7;
        const float* src = &T[row][seg8 * 32];
        unsigned short* dst = A_hi + ((size_t)(b * 1024 + hw0 + row) * 256 + seg8 * 32);
        #pragma unroll
        for (int c = 0; c < 4; ++c) {
            unsigned int ub[4];
            #pragma unroll
            for (int p = 0; p < 4; ++p) {
                unsigned int lo = f16_rne(src[c * 8 + 2 * p] * A_SCALE);
                unsigned int hi = f16_rne(src[c * 8 + 2 * p + 1] * A_SCALE);
                ub[p] = lo | (hi << 16);
            }
            *(uint4*)(dst + c * 8) = make_uint4(ub[0], ub[1], ub[2], ub[3]);
        }
    }
}

// ---- dist2: fp16 MFMA, 128 rows x ALL 1024 codes per block ----
// B reg-staged (depth 2), raw s_barrier + lgkmcnt(0) only: the compiler emits
// counted vmcnt waits for the reg loads, so prefetches remain in flight across
// barriers (no per-step vmcnt(0) drain). Step t: issue chunk t+2 into regs;
// ds_read + 16 MFMA on chunk t from buf[t&1]; ds_write chunk t+1 into the
// other buffer; lgkmcnt(0); s_barrier. sched_barrier(0) pins region order.
#define DSTEP(T, CUR, W0, W1, I0, I1)                                                   \
  {                                                                                     \
    const int t_ = (T);                                                                 \
    if (t_ + 2 < 64) {                                                                  \
      const int nc_ = (t_ + 2) >> 3, ns_ = (t_ + 2) & 7;                                \
      I0 = *(const uint4*)(B_hi + (((size_t)(nc_ * 128 + arsub)) << 8) + ns_ * 32 + aq);      \
      I1 = *(const uint4*)(B_hi + (((size_t)(nc_ * 128 + 64 + arsub)) << 8) + ns_ * 32 + aq); \
    }                                                                                   \
    __builtin_amdgcn_sched_barrier(0);                                                  \
    const char* bb_ = smem + 65536 + ((CUR) << 13);                                     \
    const int sv_ = t_ & 7;                                                             \
    half8 af[4], bf[4];                                                                 \
    _Pragma("unroll") for (int i = 0; i < 4; ++i)                                       \
      af[i] = *(const half8*)(smem + sv_ * 8192 + (wr * 64 + i * 16 + l16) * 64 + rdoff); \
    _Pragma("unroll") for (int j = 0; j < 4; ++j)                                       \
      bf[j] = *(const half8*)(bb_ + (wc * 64 + j * 16 + l16) * 64 + rdoff);             \
    __builtin_amdgcn_s_setprio(1);                                                      \
    _Pragma("unroll") for (int i = 0; i < 4; ++i)                                       \
      _Pragma("unroll") for (int j = 0; j < 4; ++j)                                     \
        acc[i][j] = __builtin_amdgcn_mfma_f32_16x16x32_f16(af[i], bf[j], acc[i][j], 0, 0, 0); \
    __builtin_amdgcn_s_setprio(0);                                                      \
    __builtin_amdgcn_sched_barrier(0);                                                  \
    if (t_ + 1 < 64) {                                                                  \
      char* nb_ = smem + 65536 + ((1 ^ (CUR)) << 13) + w * 1024 + (lane << 4);          \
      *(uint4*)nb_ = W0;                                                                \
      *(uint4*)(nb_ + 4096) = W1;                                                       \
    }                                                                                   \
    asm volatile("s_waitcnt lgkmcnt(0)" ::: "memory");                                  \
    __builtin_amdgcn_s_barrier();                                                       \
    __builtin_amdgcn_sched_barrier(0);                                                  \
  }

__launch_bounds__(256, 2)
__global__ void dist2_kernel(const unsigned short* __restrict__ A_hi,
                             const unsigned short* __restrict__ B_hi,
                             const float* __restrict__ xnorm,
                             const float* __restrict__ enorm,
                             int* __restrict__ fidx,
                             int* __restrict__ amb,
                             int* __restrict__ amb_count) {
    __shared__ __align__(16) char smem[81920];            // As 64KB | Bs 2x8KB
    unsigned long long* red = (unsigned long long*)(smem + 65536); // overlay buf0

    const int tid  = threadIdx.x;
    const int w = tid >> 6, lane = tid & 63;
    const int l16 = lane & 15, quad = lane >> 4;
    const int wc = w & 1, wr = w >> 1;
    const int row0 = blockIdx.x * 128;

    // staging constants: lane -> (row = base + lane/4, granule lane&3), global
    // source pre-swizzled (inverse of the read swizzle; involution).
    const int aq    = (((lane & 3) ^ ((lane >> 3) & 3)) << 3);  // shorts
    const int arsub = (w << 4) + (lane >> 2);
    // read-side swizzle: granule (quad ^ ((l16>>1)&3)) of the fragment row
    const int rdoff = ((quad ^ ((l16 >> 1) & 3)) << 4);         // bytes

    // prologue: A tile (64KB) via gld16; B chunks 0,1 into regs.
    #pragma unroll
    for (int t = 0; t < 16; ++t) {
        const int arow = ((t & 1) << 6) + arsub;
        const int s    = t >> 1;
        gld16(A_hi + (((size_t)(row0 + arow)) << 8) + s * 32 + aq,
              smem + t * 4096 + w * 1024);
    }
    uint4 p0, p1, q0, q1;
    p0 = *(const uint4*)(B_hi + (((size_t)(arsub)) << 8) + aq);              // chunk 0
    p1 = *(const uint4*)(B_hi + (((size_t)(64 + arsub)) << 8) + aq);
    q0 = *(const uint4*)(B_hi + (((size_t)(arsub)) << 8) + 32 + aq);         // chunk 1
    q1 = *(const uint4*)(B_hi + (((size_t)(64 + arsub)) << 8) + 32 + aq);
    {   // ds_write chunk 0 -> buf0 (its vmcnt wait also drains the A gld16s)
        char* d0 = smem + 65536 + w * 1024 + (lane << 4);
        *(uint4*)d0 = p0;
        *(uint4*)(d0 + 4096) = p1;
    }
    asm volatile("s_waitcnt lgkmcnt(0)" ::: "memory");
    __builtin_amdgcn_s_barrier();
    __builtin_amdgcn_sched_barrier(0);

    // per-thread state
    float xnr[4][4];
    #pragma unroll
    for (int i = 0; i < 4; ++i)
        #pragma unroll
        for (int r = 0; r < 4; ++r)
            xnr[i][r] = xnorm[row0 + wr * 64 + i * 16 + quad * 4 + r];

    const float INF = __uint_as_float(0x7F800000u);
    float m1[4][4], m2[4][4];
    unsigned int ix[4][4];
    #pragma unroll
    for (int i = 0; i < 4; ++i)
        #pragma unroll
        for (int r = 0; r < 4; ++r) { m1[i][r] = INF; m2[i][r] = INF; ix[i][r] = 0u; }

    // main loop: 8 code-chunks x 8 K-steps, 2-step unrolled for buffer parity.
    for (int cb = 0; cb < 8; ++cb) {
        f32x4 acc[4][4];
        #pragma unroll
        for (int i = 0; i < 4; ++i)
            #pragma unroll
            for (int j = 0; j < 4; ++j) acc[i][j] = (f32x4){0.f, 0.f, 0.f, 0.f};

        #pragma unroll
        for (int sh = 0; sh < 4; ++sh) {
            DSTEP(cb * 8 + 2 * sh,     0, q0, q1, p0, p1);   // even: buf0; write q; issue p
            DSTEP(cb * 8 + 2 * sh + 1, 1, p0, p1, q0, q1);   // odd:  buf1; write p; issue q
        }

        // fold chunk into running float top-2 + argmin idx.
        float enj[4];
        #pragma unroll
        for (int j = 0; j < 4; ++j) enj[j] = enorm[cb * 128 + wc * 64 + j * 16 + l16];
        #pragma unroll
        for (int i = 0; i < 4; ++i) {
            #pragma unroll
            for (int r = 0; r < 4; ++r) {
                const float xn = xnr[i][r];
                float a = m1[i][r], b = m2[i][r];
                unsigned int id = ix[i][r];
                #pragma unroll
                for (int j = 0; j < 4; ++j) {
                    const unsigned int n = cb * 128 + wc * 64 + j * 16 + l16;
                    float sc = fmaf(acc[i][j][r], -INV_SCALE2, xn + enj[j]);
                    bool c = sc < a;
                    b = fminf(b, fmaxf(a, sc));
                    a = fminf(a, sc);
                    id = c ? n : id;
                }
                m1[i][r] = a; m2[i][r] = b; ix[i][r] = id;
            }
        }
    }

    // one reduce per row: u64 pack now, 16-lane shfl tree, wc-pair merge in LDS.
    #pragma unroll
    for (int i = 0; i < 4; ++i) {
        #pragma unroll
        for (int r = 0; r < 4; ++r) {
            unsigned long long a1 = ((unsigned long long)mono(m1[i][r]) << 32) | ix[i][r];
            unsigned long long a2 = ((unsigned long long)mono(m2[i][r]) << 32) | 0xFFFFFFFFull;
            #pragma unroll
            for (int m = 1; m < 16; m <<= 1) {
                unsigned long long u1 = __shfl_xor(a1, m, 16);
                unsigned long long u2 = __shfl_xor(a2, m, 16);
                if (u1 < a1) { a2 = (a1 < u2) ? a1 : u2; a1 = u1; }
                else         { a2 = (a2 < u1) ? a2 : u1; }
            }
            if (l16 == 0) {
                int rowl = wr * 64 + i * 16 + quad * 4 + r;
                red[(rowl * 2 + wc) * 2 + 0] = a1;
                red[(rowl * 2 + wc) * 2 + 1] = a2;
            }
        }
    }
    __syncthreads();
    if (tid < 128) {
        unsigned long long a1 = red[(tid * 2 + 0) * 2 + 0];
        unsigned long long a2 = red[(tid * 2 + 0) * 2 + 1];
        unsigned long long b1 = red[(tid * 2 + 1) * 2 + 0];
        unsigned long long b2 = red[(tid * 2 + 1) * 2 + 1];
        if (b1 < a1) { a2 = (a1 < b2) ? a1 : b2; a1 = b1; }
        else         { a2 = (a2 < b1) ? a2 : b1; }
        const int row = row0 + tid;
        fidx[row] = (int)(a1 & 0xFFFFFFFFull);
        float s1 = unmono((unsigned int)(a1 >> 32));
        float s2 = unmono((unsigned int)(a2 >> 32));
        if (s2 - s1 <= FLAG_MARGIN) {
            int slot = atomicAdd(amb_count, 1);
            if (slot < AMB_CAP) amb[slot] = row;
        }
    }
}

// ---- rescue (4 rows/group): thread owns 4 consecutive codes x 4 rows.
// d-loop software-pipelined depth 8; fp64 add order ascending d (bit-identical).
__launch_bounds__(256)
__global__ void rescue4_kernel(const float* __restrict__ z_e,
                               const float* __restrict__ embT,
                               const float* __restrict__ xnorm,
                               const float* __restrict__ enorm,
                               const int* __restrict__ amb,
                               const int* __restrict__ amb_count,
                               int* __restrict__ fidx) {
    __shared__ float xs[4][256];
    __shared__ int rows[4];
    __shared__ unsigned long long pm[4][257];
    const int tid = threadIdx.x;
    int cnt = *amb_count;
    if (cnt > AMB_CAP) cnt = AMB_CAP;
    if (cnt <= 0) return;
    const int ngroups = (cnt + 3) >> 2;
    for (int g = blockIdx.x; g < ngroups; g += gridDim.x) {
        if (tid < 4) {
            int e = g * 4 + tid;
            rows[tid] = amb[e < cnt ? e : (cnt - 1)];   // pad with dup (benign)
        }
        __syncthreads();
        {   // stage x rows: thread -> (row j, 4 d-elements)
            const int j = tid >> 6, d0 = (tid & 63) * 4;
            const int row = rows[j];
            const int b = row >> 10, hw = row & 1023;
            const float* zp = z_e + (size_t)b * 262144 + hw;
            #pragma unroll
            for (int i = 0; i < 4; ++i)
                xs[j][d0 + i] = zp[(size_t)(d0 + i) * 1024];
        }
        __syncthreads();

        double acc[4][4];                       // [code c][row j], static idx only
        #pragma unroll
        for (int c = 0; c < 4; ++c)
            #pragma unroll
            for (int j = 0; j < 4; ++j) acc[c][j] = 0.0;

        const float* ep = embT + 4 * tid;
        for (int d0 = 0; d0 < D_DIM; d0 += 8) {
            float4 ev[8];
            #pragma unroll
            for (int u = 0; u < 8; ++u)
                ev[u] = *(const float4*)(ep + (size_t)(d0 + u) * K_CODES);
            #pragma unroll
            for (int u = 0; u < 8; ++u) {
                const int d = d0 + u;
                double e0 = (double)ev[u].x, e1 = (double)ev[u].y;
                double e2 = (double)ev[u].z, e3 = (double)ev[u].w;
                double x0 = (double)xs[0][d], x1 = (double)xs[1][d];
                double x2 = (double)xs[2][d], x3 = (double)xs[3][d];
                acc[0][0] += x0 * e0; acc[0][1] += x1 * e0; acc[0][2] += x2 * e0; acc[0][3] += x3 * e0;
                acc[1][0] += x0 * e1; acc[1][1] += x1 * e1; acc[1][2] += x2 * e1; acc[1][3] += x3 * e1;
                acc[2][0] += x0 * e2; acc[2][1] += x1 * e2; acc[2][2] += x2 * e2; acc[2][3] += x3 * e2;
                acc[3][0] += x0 * e3; acc[3][1] += x1 * e3; acc[3][2] += x2 * e3; acc[3][3] += x3 * e3;
            }
        }

        float xnr[4];
        #pragma unroll
        for (int j = 0; j < 4; ++j) xnr[j] = xnorm[rows[j]];

        unsigned long long mm[4] = {~0ull, ~0ull, ~0ull, ~0ull};
        #pragma unroll
        for (int c = 0; c < 4; ++c) {
            const int k = 4 * tid + c;
            const float en = enorm[k];
            #pragma unroll
            for (int j = 0; j < 4; ++j) {
                float dv = (float)acc[c][j];
                float t = xnr[j] + en;
                float s = t - 2.f * dv;
                unsigned long long p = ((unsigned long long)mono(s) << 32) | (unsigned int)k;
                if (p < mm[j]) mm[j] = p;
            }
        }
        #pragma unroll
        for (int j = 0; j < 4; ++j) pm[j][tid] = mm[j];
        __syncthreads();
        for (int s = 128; s > 0; s >>= 1) {
            if (tid < s) {
                #pragma unroll
                for (int j = 0; j < 4; ++j)
                    if (pm[j][tid + s] < pm[j][tid]) pm[j][tid] = pm[j][tid + s];
            }
            __syncthreads();
        }
        if (tid < 4) fidx[rows[tid]] = (int)(pm[tid][0] & 0xFFFFFFFFull);
        __syncthreads();
    }
}

// ---- epilogue: hw-vectorized (16B/lane) + fused finalize (last-block-done) ----
__global__ void epilogue_kernel(const float* __restrict__ z_e,
                                const float* __restrict__ emb,
                                const int* __restrict__ fidx,
                                float* __restrict__ out,
                                int* __restrict__ counts,
                                float* __restrict__ loss_sum,
                                int* __restrict__ done) {
    __shared__ int   kb[64];
    __shared__ float rs[256];
    __shared__ int   lastFlag;
    const int tid = threadIdx.x;
    const int rcb = blockIdx.x;
    const int b   = rcb >> 4;
    const int hw0 = (rcb & 15) << 6;

    if (tid < 64) {
        int k = fidx[rcb * 64 + tid];
        kb[tid] = k;
        out[(size_t)IDX_OFF + (size_t)rcb * 64 + tid] = (float)k;
        atomicAdd(&counts[k], 1);
    }
    __syncthreads();

    const int j4 = (tid & 15) << 2;   // hw offset within the 64-chunk, float4
    const int dq = tid >> 4;          // 16 d-slices
    const float* e0 = emb + (size_t)kb[j4 + 0] * D_DIM;
    const float* e1 = emb + (size_t)kb[j4 + 1] * D_DIM;
    const float* e2 = emb + (size_t)kb[j4 + 2] * D_DIM;
    const float* e3 = emb + (size_t)kb[j4 + 3] * D_DIM;
    const size_t base = (size_t)b * 262144 + hw0 + j4;
    float ls = 0.f;
    #pragma unroll 4
    for (int d = dq; d < D_DIM; d += 16) {
        size_t off = base + ((size_t)d << 10);
        float4 x = *(const float4*)(z_e + off);
        float4 q;
        q.x = e0[d]; q.y = e1[d]; q.z = e2[d]; q.w = e3[d];
        *(float4*)(out + off) = q;
        float d0 = q.x - x.x, d1 = q.y - x.y, d2 = q.z - x.z, d3 = q.w - x.w;
        ls += d0 * d0; ls += d1 * d1; ls += d2 * d2; ls += d3 * d3;
    }
    rs[tid] = ls;
    __syncthreads();
    for (int s = 128; s > 0; s >>= 1) {
        if (tid < s) rs[tid] += rs[tid + s];
        __syncthreads();
    }
    if (tid == 0) atomicAdd(loss_sum, rs[0]);

    // fused finalize: last block to finish computes loss + perplexity.
    __threadfence();
    if (tid == 0) lastFlag = (atomicAdd(done, 1) == (int)gridDim.x - 1);
    __syncthreads();
    if (lastFlag) {
        __threadfence();
        float s = 0.f;
        for (int k = tid; k < K_CODES; k += 256) {
            int c = atomicAdd(&counts[k], 0);          // device-coherent read
            float p = (float)c / 65536.0f;
            s += p * logf(p + 1e-10f);
        }
        rs[tid] = s;
        __syncthreads();
        for (int st = 128; st > 0; st >>= 1) {
            if (tid < st) rs[tid] += rs[tid + st];
            __syncthreads();
        }
        if (tid == 0) {
            float L = atomicAdd(loss_sum, 0.f);        // device-coherent read
            out[N_ELEM]     = L * 1.25f / 16777216.0f;
            out[N_ELEM + 1] = expf(-rs[0]);
        }
    }
}

extern "C" void kernel_launch(void* const* d_in, const int* in_sizes, int n_in,
                              void* d_out, int out_size, void* d_ws, size_t ws_size,
                              hipStream_t stream) {
    const float* z_e = (const float*)d_in[0];
    const float* emb = (const float*)d_in[1];
    float* out = (float*)d_out;
    char*  ws  = (char*)d_ws;

    // big scratch inside d_out (overwritten by epilogue)
    unsigned short* A_hi = (unsigned short*)d_out;

    float*          enorm    = (float*)ws;
    float*          xnorm    = (float*)(ws + 4096);
    int*            fidx     = (int*)(ws + 266240);
    int*            counts   = (int*)(ws + 528384);
    float*          loss_sum = (float*)(ws + 532480);
    int*            amb_cnt  = (int*)(ws + 532484);
    int*            amb      = (int*)(ws + 532488);
    int*            done     = (int*)(ws + 794632);
    unsigned short* B_hi     = (unsigned short*)(ws + 794752);
    float*          embT     = (float*)(ws + 1319040);

    prep_kernel<<<2052, 256, 0, stream>>>(z_e, emb, A_hi, xnorm, enorm, B_hi, embT,
                                          counts, loss_sum, amb_cnt, done);
    dist2_kernel<<<512, 256, 0, stream>>>(A_hi, B_hi, xnorm, enorm, fidx, amb, amb_cnt);
    rescue4_kernel<<<1024, 256, 0, stream>>>(z_e, embT, xnorm, enorm, amb, amb_cnt, fidx);
    epilogue_kernel<<<N_ROWS / 64, 256, 0, stream>>>(z_e, emb, fidx, out, counts, loss_sum, done);
}

// Round 9
// 280.575 us; speedup vs baseline: 1.5083x; 1.5083x over previous
//
#include <hip/hip_runtime.h>
#include <hip/hip_fp16.h>
#include <stdint.h>

// VQ-VAE forward on MI355X — fp16-MFMA fast path + fp64 rescue for exact np argmin.
// Round 17: revert the finalize-fusion (round 16's epilogue ran 197us at 1.1%
// VALUBusy: per-thread __threadfence() = device-scope release = s_waitcnt
// vmcnt(0) + buffer_wbl2 L2-writeback, serializing every block's 64KB store
// stream; the saved dispatch was ~5us, the fence cost ~150us). Epilogue back to
// round-14 form + separate 1-block finalize. KEPT: prep fusion, dist2 reg-staged
// B double-buffer with raw s_barrier + lgkmcnt(0) (passed correctness in r16;
// perf still unmeasured — epilogue filled the top-5), rescue depth-8 pipeline.
//
// z_e: [64, 256, 32, 32] f32 ; emb: [1024, 256] f32
// out: z_q_st (16777216) | loss (1) | perplexity (1) | idx (65536, as float)
//
// Big scratch in d_out's z_q region (overwritten by epilogue last):
//   out bytes [0, 32MB)       A_hi  fp16[65536][256]  (transposed z_e, x16)
// ws layout (bytes):
//   [0,      4096)    enorm f32[1024]      [4096,   266240)  xnorm f32[65536]
//   [266240, 528384)  fidx  i32[65536]     [528384, 532480)  counts i32[1024]
//   [532480, 532484)  loss_sum             [532484, 532488)  amb_count
//   [532488, 794632)  amb i32[65536]
//   [794752, 1319040) B_hi fp16[1024][256] (e*4096)
//   [1319040,2367616) embT f32[256][1024]

#define D_DIM   256
#define K_CODES 1024
#define N_ROWS  65536
#define N_ELEM  16777216
#define IDX_OFF 16777218
#define FLAG_MARGIN 1.5e-4f
#define AMB_CAP 65536
#define A_SCALE 16.0f
#define B_SCALE 4096.0f
#define INV_SCALE2 3.0517578125e-05f   /* 2 / (16*4096) = 2^-15, exact */

typedef short short8 __attribute__((ext_vector_type(8)));
typedef _Float16 half8 __attribute__((ext_vector_type(8)));
typedef float f32x4  __attribute__((ext_vector_type(4)));

__device__ __forceinline__ unsigned int mono(float s) {
    unsigned int u = __float_as_uint(s);
    return (u & 0x80000000u) ? ~u : (u | 0x80000000u);
}
__device__ __forceinline__ float unmono(unsigned int u) {
    return __uint_as_float((u & 0x80000000u) ? (u & 0x7FFFFFFFu) : ~u);
}
__device__ __forceinline__ unsigned short f16_rne(float x) {
    return __half_as_ushort(__float2half(x));   // RNE
}
__device__ __forceinline__ void gld16(const void* g, void* l) {
    __builtin_amdgcn_global_load_lds(
        (const __attribute__((address_space(1))) unsigned int*)g,
        (__attribute__((address_space(3))) unsigned int*)l, 16, 0, 0);
}

// ---- fused prep: blocks 0-3 = emb path (enorm/B_hi/embT + zero counters);
//      blocks 4..2051 = z_e transpose -> A_hi fp16(x16) + xnorm ----
__launch_bounds__(256)
__global__ void prep_kernel(const float* __restrict__ z_e,
                            const float* __restrict__ emb,
                            unsigned short* __restrict__ A_hi,
                            float* __restrict__ xnorm,
                            float* __restrict__ enorm,
                            unsigned short* __restrict__ B_hi,
                            float* __restrict__ embT,
                            int* __restrict__ counts,
                            float* __restrict__ loss_sum,
                            int* __restrict__ amb_count) {
#pragma clang fp contract(off)
    __shared__ float T[32][257];
    __shared__ float H[32][2];
    const int bid = blockIdx.x;
    const int tid = threadIdx.x;

    if (bid < 4) {
        // emb path: one code per thread; rows register-batched as float4 for ILP.
        const int k = bid * 256 + tid;
        counts[k] = 0;
        if (bid == 0 && tid == 0) { *loss_sum = 0.f; *amb_count = 0; }
        const float* p = emb + (size_t)k * D_DIM;
        unsigned int* dstB = (unsigned int*)(B_hi + (size_t)k * D_DIM);
        float halfv[2];
        #pragma unroll
        for (int h = 0; h < 2; ++h) {
            float r[8];
            #pragma unroll
            for (int qq = 0; qq < 2; ++qq) {
                const float* qb = p + h * 128 + qq * 64;
                float4 ev[16];
                #pragma unroll
                for (int m = 0; m < 16; ++m)
                    ev[m] = *(const float4*)(qb + 4 * m);
                // np-pairwise partials: r[j] accumulated over ascending i blocks.
                #pragma unroll
                for (int t = 0; t < 8; ++t) {
                    const float4 a = ev[2 * t], b = ev[2 * t + 1];
                    if (qq == 0 && t == 0) {
                        r[0] = a.x * a.x; r[1] = a.y * a.y; r[2] = a.z * a.z; r[3] = a.w * a.w;
                        r[4] = b.x * b.x; r[5] = b.y * b.y; r[6] = b.z * b.z; r[7] = b.w * b.w;
                    } else {
                        r[0] += a.x * a.x; r[1] += a.y * a.y; r[2] += a.z * a.z; r[3] += a.w * a.w;
                        r[4] += b.x * b.x; r[5] += b.y * b.y; r[6] += b.z * b.z; r[7] += b.w * b.w;
                    }
                }
                // B_hi: sequential-d fp16(x4096) packing, 8 floats per uint4 store.
                #pragma unroll
                for (int m = 0; m < 16; m += 2) {
                    const float4 a = ev[m], b = ev[m + 1];
                    unsigned int u0 = f16_rne(a.x * B_SCALE) | ((unsigned int)f16_rne(a.y * B_SCALE) << 16);
                    unsigned int u1 = f16_rne(a.z * B_SCALE) | ((unsigned int)f16_rne(a.w * B_SCALE) << 16);
                    unsigned int u2 = f16_rne(b.x * B_SCALE) | ((unsigned int)f16_rne(b.y * B_SCALE) << 16);
                    unsigned int u3 = f16_rne(b.z * B_SCALE) | ((unsigned int)f16_rne(b.w * B_SCALE) << 16);
                    *(uint4*)(dstB + (h * 64 + qq * 32 + 2 * m)) = make_uint4(u0, u1, u2, u3);
                }
                // embT: per-lane k, fixed d per store -> coalesced across lanes.
                const int dbase = h * 128 + qq * 64;
                #pragma unroll
                for (int m = 0; m < 16; ++m) {
                    embT[(size_t)(dbase + 4 * m + 0) * K_CODES + k] = ev[m].x;
                    embT[(size_t)(dbase + 4 * m + 1) * K_CODES + k] = ev[m].y;
                    embT[(size_t)(dbase + 4 * m + 2) * K_CODES + k] = ev[m].z;
                    embT[(size_t)(dbase + 4 * m + 3) * K_CODES + k] = ev[m].w;
                }
            }
            halfv[h] = ((r[0] + r[1]) + (r[2] + r[3])) + ((r[4] + r[5]) + (r[6] + r[7]));
        }
        enorm[k] = halfv[0] + halfv[1];
        return;
    }

    // a path: transpose one [32 hw x 256 d] tile of z_e.
    const int bx = bid - 4;                    // 2048 tiles
    const int b = bx >> 5, hw0 = (bx & 31) << 5;
    const float* zb = z_e + (size_t)b * 262144 + hw0;
    #pragma unroll 4
    for (int it = 0; it < 8; ++it) {
        int flat = it * 256 + tid;             // 2048 float4
        int d = flat >> 3;
        int hw4 = (flat & 7) << 2;
        float4 v = *(const float4*)(zb + (size_t)d * 1024 + hw4);
        T[hw4 + 0][d] = v.x; T[hw4 + 1][d] = v.y;
        T[hw4 + 2][d] = v.z; T[hw4 + 3][d] = v.w;
    }
    __syncthreads();
    if (tid < 64) {                            // np pairwise tree per 128-half
        int row = tid >> 1, h = tid & 1;
        const float* q = &T[row][h * 128];
        float r[8];
        #pragma unroll
        for (int j = 0; j < 8; ++j) { float x = q[j]; r[j] = x * x; }
        for (int i = 8; i < 128; i += 8)
            #pragma unroll
            for (int j = 0; j < 8; ++j) { float x = q[i + j]; r[j] = r[j] + x * x; }
        H[row][h] = ((r[0] + r[1]) + (r[2] + r[3])) + ((r[4] + r[5]) + (r[6] + r[7]));
    }
    __syncthreads();
    if (tid < 32) xnorm[b * 1024 + hw0 + tid] = H[tid][0] + H[tid][1];
    {   // fp16(x16) convert: thread -> (row, 32-d segment)
        int row = tid >> 3, seg8 = tid & 7;
        const float* src = &T[row][seg8 * 32];
        unsigned short* dst = A_hi + ((size_t)(b * 1024 + hw0 + row) * 256 + seg8 * 32);
        #pragma unroll
        for (int c = 0; c < 4; ++c) {
            unsigned int ub[4];
            #pragma unroll
            for (int p = 0; p < 4; ++p) {
                unsigned int lo = f16_rne(src[c * 8 + 2 * p] * A_SCALE);
                unsigned int hi = f16_rne(src[c * 8 + 2 * p + 1] * A_SCALE);
                ub[p] = lo | (hi << 16);
            }
            *(uint4*)(dst + c * 8) = make_uint4(ub[0], ub[1], ub[2], ub[3]);
        }
    }
}

// ---- dist2: fp16 MFMA, 128 rows x ALL 1024 codes per block ----
// B reg-staged (depth 2), raw s_barrier + lgkmcnt(0) only: the compiler emits
// counted vmcnt waits for the reg loads, so prefetches remain in flight across
// barriers (no per-step vmcnt(0) drain). Step t: issue chunk t+2 into regs;
// ds_read + 16 MFMA on chunk t from buf[t&1]; ds_write chunk t+1 into the
// other buffer; lgkmcnt(0); s_barrier. sched_barrier(0) pins region order.
#define DSTEP(T, CUR, W0, W1, I0, I1)                                                   \
  {                                                                                     \
    const int t_ = (T);                                                                 \
    if (t_ + 2 < 64) {                                                                  \
      const int nc_ = (t_ + 2) >> 3, ns_ = (t_ + 2) & 7;                                \
      I0 = *(const uint4*)(B_hi + (((size_t)(nc_ * 128 + arsub)) << 8) + ns_ * 32 + aq);      \
      I1 = *(const uint4*)(B_hi + (((size_t)(nc_ * 128 + 64 + arsub)) << 8) + ns_ * 32 + aq); \
    }                                                                                   \
    __builtin_amdgcn_sched_barrier(0);                                                  \
    const char* bb_ = smem + 65536 + ((CUR) << 13);                                     \
    const int sv_ = t_ & 7;                                                             \
    half8 af[4], bf[4];                                                                 \
    _Pragma("unroll") for (int i = 0; i < 4; ++i)                                       \
      af[i] = *(const half8*)(smem + sv_ * 8192 + (wr * 64 + i * 16 + l16) * 64 + rdoff); \
    _Pragma("unroll") for (int j = 0; j < 4; ++j)                                       \
      bf[j] = *(const half8*)(bb_ + (wc * 64 + j * 16 + l16) * 64 + rdoff);             \
    __builtin_amdgcn_s_setprio(1);                                                      \
    _Pragma("unroll") for (int i = 0; i < 4; ++i)                                       \
      _Pragma("unroll") for (int j = 0; j < 4; ++j)                                     \
        acc[i][j] = __builtin_amdgcn_mfma_f32_16x16x32_f16(af[i], bf[j], acc[i][j], 0, 0, 0); \
    __builtin_amdgcn_s_setprio(0);                                                      \
    __builtin_amdgcn_sched_barrier(0);                                                  \
    if (t_ + 1 < 64) {                                                                  \
      char* nb_ = smem + 65536 + ((1 ^ (CUR)) << 13) + w * 1024 + (lane << 4);          \
      *(uint4*)nb_ = W0;                                                                \
      *(uint4*)(nb_ + 4096) = W1;                                                       \
    }                                                                                   \
    asm volatile("s_waitcnt lgkmcnt(0)" ::: "memory");                                  \
    __builtin_amdgcn_s_barrier();                                                       \
    __builtin_amdgcn_sched_barrier(0);                                                  \
  }

__launch_bounds__(256, 2)
__global__ void dist2_kernel(const unsigned short* __restrict__ A_hi,
                             const unsigned short* __restrict__ B_hi,
                             const float* __restrict__ xnorm,
                             const float* __restrict__ enorm,
                             int* __restrict__ fidx,
                             int* __restrict__ amb,
                             int* __restrict__ amb_count) {
    __shared__ __align__(16) char smem[81920];            // As 64KB | Bs 2x8KB
    unsigned long long* red = (unsigned long long*)(smem + 65536); // overlay buf0

    const int tid  = threadIdx.x;
    const int w = tid >> 6, lane = tid & 63;
    const int l16 = lane & 15, quad = lane >> 4;
    const int wc = w & 1, wr = w >> 1;
    const int row0 = blockIdx.x * 128;

    // staging constants: lane -> (row = base + lane/4, granule lane&3), global
    // source pre-swizzled (inverse of the read swizzle; involution).
    const int aq    = (((lane & 3) ^ ((lane >> 3) & 3)) << 3);  // shorts
    const int arsub = (w << 4) + (lane >> 2);
    // read-side swizzle: granule (quad ^ ((l16>>1)&3)) of the fragment row
    const int rdoff = ((quad ^ ((l16 >> 1) & 3)) << 4);         // bytes

    // prologue: A tile (64KB) via gld16; B chunks 0,1 into regs.
    #pragma unroll
    for (int t = 0; t < 16; ++t) {
        const int arow = ((t & 1) << 6) + arsub;
        const int s    = t >> 1;
        gld16(A_hi + (((size_t)(row0 + arow)) << 8) + s * 32 + aq,
              smem + t * 4096 + w * 1024);
    }
    uint4 p0, p1, q0, q1;
    p0 = *(const uint4*)(B_hi + (((size_t)(arsub)) << 8) + aq);              // chunk 0
    p1 = *(const uint4*)(B_hi + (((size_t)(64 + arsub)) << 8) + aq);
    q0 = *(const uint4*)(B_hi + (((size_t)(arsub)) << 8) + 32 + aq);         // chunk 1
    q1 = *(const uint4*)(B_hi + (((size_t)(64 + arsub)) << 8) + 32 + aq);
    {   // ds_write chunk 0 -> buf0 (its vmcnt wait also drains the A gld16s)
        char* d0 = smem + 65536 + w * 1024 + (lane << 4);
        *(uint4*)d0 = p0;
        *(uint4*)(d0 + 4096) = p1;
    }
    asm volatile("s_waitcnt lgkmcnt(0)" ::: "memory");
    __builtin_amdgcn_s_barrier();
    __builtin_amdgcn_sched_barrier(0);

    // per-thread state
    float xnr[4][4];
    #pragma unroll
    for (int i = 0; i < 4; ++i)
        #pragma unroll
        for (int r = 0; r < 4; ++r)
            xnr[i][r] = xnorm[row0 + wr * 64 + i * 16 + quad * 4 + r];

    const float INF = __uint_as_float(0x7F800000u);
    float m1[4][4], m2[4][4];
    unsigned int ix[4][4];
    #pragma unroll
    for (int i = 0; i < 4; ++i)
        #pragma unroll
        for (int r = 0; r < 4; ++r) { m1[i][r] = INF; m2[i][r] = INF; ix[i][r] = 0u; }

    // main loop: 8 code-chunks x 8 K-steps, 2-step unrolled for buffer parity.
    for (int cb = 0; cb < 8; ++cb) {
        f32x4 acc[4][4];
        #pragma unroll
        for (int i = 0; i < 4; ++i)
            #pragma unroll
            for (int j = 0; j < 4; ++j) acc[i][j] = (f32x4){0.f, 0.f, 0.f, 0.f};

        #pragma unroll
        for (int sh = 0; sh < 4; ++sh) {
            DSTEP(cb * 8 + 2 * sh,     0, q0, q1, p0, p1);   // even: buf0; write q; issue p
            DSTEP(cb * 8 + 2 * sh + 1, 1, p0, p1, q0, q1);   // odd:  buf1; write p; issue q
        }

        // fold chunk into running float top-2 + argmin idx.
        float enj[4];
        #pragma unroll
        for (int j = 0; j < 4; ++j) enj[j] = enorm[cb * 128 + wc * 64 + j * 16 + l16];
        #pragma unroll
        for (int i = 0; i < 4; ++i) {
            #pragma unroll
            for (int r = 0; r < 4; ++r) {
                const float xn = xnr[i][r];
                float a = m1[i][r], b = m2[i][r];
                unsigned int id = ix[i][r];
                #pragma unroll
                for (int j = 0; j < 4; ++j) {
                    const unsigned int n = cb * 128 + wc * 64 + j * 16 + l16;
                    float sc = fmaf(acc[i][j][r], -INV_SCALE2, xn + enj[j]);
                    bool c = sc < a;
                    b = fminf(b, fmaxf(a, sc));
                    a = fminf(a, sc);
                    id = c ? n : id;
                }
                m1[i][r] = a; m2[i][r] = b; ix[i][r] = id;
            }
        }
    }

    // one reduce per row: u64 pack now, 16-lane shfl tree, wc-pair merge in LDS.
    #pragma unroll
    for (int i = 0; i < 4; ++i) {
        #pragma unroll
        for (int r = 0; r < 4; ++r) {
            unsigned long long a1 = ((unsigned long long)mono(m1[i][r]) << 32) | ix[i][r];
            unsigned long long a2 = ((unsigned long long)mono(m2[i][r]) << 32) | 0xFFFFFFFFull;
            #pragma unroll
            for (int m = 1; m < 16; m <<= 1) {
                unsigned long long u1 = __shfl_xor(a1, m, 16);
                unsigned long long u2 = __shfl_xor(a2, m, 16);
                if (u1 < a1) { a2 = (a1 < u2) ? a1 : u2; a1 = u1; }
                else         { a2 = (a2 < u1) ? a2 : u1; }
            }
            if (l16 == 0) {
                int rowl = wr * 64 + i * 16 + quad * 4 + r;
                red[(rowl * 2 + wc) * 2 + 0] = a1;
                red[(rowl * 2 + wc) * 2 + 1] = a2;
            }
        }
    }
    __syncthreads();
    if (tid < 128) {
        unsigned long long a1 = red[(tid * 2 + 0) * 2 + 0];
        unsigned long long a2 = red[(tid * 2 + 0) * 2 + 1];
        unsigned long long b1 = red[(tid * 2 + 1) * 2 + 0];
        unsigned long long b2 = red[(tid * 2 + 1) * 2 + 1];
        if (b1 < a1) { a2 = (a1 < b2) ? a1 : b2; a1 = b1; }
        else         { a2 = (a2 < b1) ? a2 : b1; }
        const int row = row0 + tid;
        fidx[row] = (int)(a1 & 0xFFFFFFFFull);
        float s1 = unmono((unsigned int)(a1 >> 32));
        float s2 = unmono((unsigned int)(a2 >> 32));
        if (s2 - s1 <= FLAG_MARGIN) {
            int slot = atomicAdd(amb_count, 1);
            if (slot < AMB_CAP) amb[slot] = row;
        }
    }
}

// ---- rescue (4 rows/group): thread owns 4 consecutive codes x 4 rows.
// d-loop software-pipelined depth 8; fp64 add order ascending d (bit-identical).
__launch_bounds__(256)
__global__ void rescue4_kernel(const float* __restrict__ z_e,
                               const float* __restrict__ embT,
                               const float* __restrict__ xnorm,
                               const float* __restrict__ enorm,
                               const int* __restrict__ amb,
                               const int* __restrict__ amb_count,
                               int* __restrict__ fidx) {
    __shared__ float xs[4][256];
    __shared__ int rows[4];
    __shared__ unsigned long long pm[4][257];
    const int tid = threadIdx.x;
    int cnt = *amb_count;
    if (cnt > AMB_CAP) cnt = AMB_CAP;
    if (cnt <= 0) return;
    const int ngroups = (cnt + 3) >> 2;
    for (int g = blockIdx.x; g < ngroups; g += gridDim.x) {
        if (tid < 4) {
            int e = g * 4 + tid;
            rows[tid] = amb[e < cnt ? e : (cnt - 1)];   // pad with dup (benign)
        }
        __syncthreads();
        {   // stage x rows: thread -> (row j, 4 d-elements)
            const int j = tid >> 6, d0 = (tid & 63) * 4;
            const int row = rows[j];
            const int b = row >> 10, hw = row & 1023;
            const float* zp = z_e + (size_t)b * 262144 + hw;
            #pragma unroll
            for (int i = 0; i < 4; ++i)
                xs[j][d0 + i] = zp[(size_t)(d0 + i) * 1024];
        }
        __syncthreads();

        double acc[4][4];                       // [code c][row j], static idx only
        #pragma unroll
        for (int c = 0; c < 4; ++c)
            #pragma unroll
            for (int j = 0; j < 4; ++j) acc[c][j] = 0.0;

        const float* ep = embT + 4 * tid;
        for (int d0 = 0; d0 < D_DIM; d0 += 8) {
            float4 ev[8];
            #pragma unroll
            for (int u = 0; u < 8; ++u)
                ev[u] = *(const float4*)(ep + (size_t)(d0 + u) * K_CODES);
            #pragma unroll
            for (int u = 0; u < 8; ++u) {
                const int d = d0 + u;
                double e0 = (double)ev[u].x, e1 = (double)ev[u].y;
                double e2 = (double)ev[u].z, e3 = (double)ev[u].w;
                double x0 = (double)xs[0][d], x1 = (double)xs[1][d];
                double x2 = (double)xs[2][d], x3 = (double)xs[3][d];
                acc[0][0] += x0 * e0; acc[0][1] += x1 * e0; acc[0][2] += x2 * e0; acc[0][3] += x3 * e0;
                acc[1][0] += x0 * e1; acc[1][1] += x1 * e1; acc[1][2] += x2 * e1; acc[1][3] += x3 * e1;
                acc[2][0] += x0 * e2; acc[2][1] += x1 * e2; acc[2][2] += x2 * e2; acc[2][3] += x3 * e2;
                acc[3][0] += x0 * e3; acc[3][1] += x1 * e3; acc[3][2] += x2 * e3; acc[3][3] += x3 * e3;
            }
        }

        float xnr[4];
        #pragma unroll
        for (int j = 0; j < 4; ++j) xnr[j] = xnorm[rows[j]];

        unsigned long long mm[4] = {~0ull, ~0ull, ~0ull, ~0ull};
        #pragma unroll
        for (int c = 0; c < 4; ++c) {
            const int k = 4 * tid + c;
            const float en = enorm[k];
            #pragma unroll
            for (int j = 0; j < 4; ++j) {
                float dv = (float)acc[c][j];
                float t = xnr[j] + en;
                float s = t - 2.f * dv;
                unsigned long long p = ((unsigned long long)mono(s) << 32) | (unsigned int)k;
                if (p < mm[j]) mm[j] = p;
            }
        }
        #pragma unroll
        for (int j = 0; j < 4; ++j) pm[j][tid] = mm[j];
        __syncthreads();
        for (int s = 128; s > 0; s >>= 1) {
            if (tid < s) {
                #pragma unroll
                for (int j = 0; j < 4; ++j)
                    if (pm[j][tid + s] < pm[j][tid]) pm[j][tid] = pm[j][tid + s];
            }
            __syncthreads();
        }
        if (tid < 4) fidx[rows[tid]] = (int)(pm[tid][0] & 0xFFFFFFFFull);
        __syncthreads();
    }
}

// ---- epilogue: hw-vectorized (16B/lane); no fences (round-16 lesson) ----
__global__ void epilogue_kernel(const float* __restrict__ z_e,
                                const float* __restrict__ emb,
                                const int* __restrict__ fidx,
                                float* __restrict__ out,
                                int* __restrict__ counts,
                                float* __restrict__ loss_sum) {
    __shared__ int   kb[64];
    __shared__ float rs[256];
    const int tid = threadIdx.x;
    const int rcb = blockIdx.x;
    const int b   = rcb >> 4;
    const int hw0 = (rcb & 15) << 6;

    if (tid < 64) {
        int k = fidx[rcb * 64 + tid];
        kb[tid] = k;
        out[(size_t)IDX_OFF + (size_t)rcb * 64 + tid] = (float)k;
        atomicAdd(&counts[k], 1);
    }
    __syncthreads();

    const int j4 = (tid & 15) << 2;   // hw offset within the 64-chunk, float4
    const int dq = tid >> 4;          // 16 d-slices
    const float* e0 = emb + (size_t)kb[j4 + 0] * D_DIM;
    const float* e1 = emb + (size_t)kb[j4 + 1] * D_DIM;
    const float* e2 = emb + (size_t)kb[j4 + 2] * D_DIM;
    const float* e3 = emb + (size_t)kb[j4 + 3] * D_DIM;
    const size_t base = (size_t)b * 262144 + hw0 + j4;
    float ls = 0.f;
    #pragma unroll 4
    for (int d = dq; d < D_DIM; d += 16) {
        size_t off = base + ((size_t)d << 10);
        float4 x = *(const float4*)(z_e + off);
        float4 q;
        q.x = e0[d]; q.y = e1[d]; q.z = e2[d]; q.w = e3[d];
        *(float4*)(out + off) = q;
        float d0 = q.x - x.x, d1 = q.y - x.y, d2 = q.z - x.z, d3 = q.w - x.w;
        ls += d0 * d0; ls += d1 * d1; ls += d2 * d2; ls += d3 * d3;
    }
    rs[tid] = ls;
    __syncthreads();
    for (int s = 128; s > 0; s >>= 1) {
        if (tid < s) rs[tid] += rs[tid + s];
        __syncthreads();
    }
    if (tid == 0) atomicAdd(loss_sum, rs[0]);
}

__global__ void finalize_kernel(const int* __restrict__ counts,
                                const float* __restrict__ loss_sum,
                                float* __restrict__ out) {
    __shared__ float rs[256];
    const int tid = threadIdx.x;
    float s = 0.f;
    for (int k = tid; k < K_CODES; k += 256) {
        float p = (float)counts[k] / 65536.0f;
        s += p * logf(p + 1e-10f);
    }
    rs[tid] = s;
    __syncthreads();
    for (int st = 128; st > 0; st >>= 1) {
        if (tid < st) rs[tid] += rs[tid + st];
        __syncthreads();
    }
    if (tid == 0) {
        out[N_ELEM]     = loss_sum[0] * 1.25f / 16777216.0f;
        out[N_ELEM + 1] = expf(-rs[0]);
    }
}

extern "C" void kernel_launch(void* const* d_in, const int* in_sizes, int n_in,
                              void* d_out, int out_size, void* d_ws, size_t ws_size,
                              hipStream_t stream) {
    const float* z_e = (const float*)d_in[0];
    const float* emb = (const float*)d_in[1];
    float* out = (float*)d_out;
    char*  ws  = (char*)d_ws;

    // big scratch inside d_out (overwritten by epilogue)
    unsigned short* A_hi = (unsigned short*)d_out;

    float*          enorm    = (float*)ws;
    float*          xnorm    = (float*)(ws + 4096);
    int*            fidx     = (int*)(ws + 266240);
    int*            counts   = (int*)(ws + 528384);
    float*          loss_sum = (float*)(ws + 532480);
    int*            amb_cnt  = (int*)(ws + 532484);
    int*            amb      = (int*)(ws + 532488);
    unsigned short* B_hi     = (unsigned short*)(ws + 794752);
    float*          embT     = (float*)(ws + 1319040);

    prep_kernel<<<2052, 256, 0, stream>>>(z_e, emb, A_hi, xnorm, enorm, B_hi, embT,
                                          counts, loss_sum, amb_cnt);
    dist2_kernel<<<512, 256, 0, stream>>>(A_hi, B_hi, xnorm, enorm, fidx, amb, amb_cnt);
    rescue4_kernel<<<1024, 256, 0, stream>>>(z_e, embT, xnorm, enorm, amb, amb_cnt, fidx);
    epilogue_kernel<<<N_ROWS / 64, 256, 0, stream>>>(z_e, emb, fidx, out, counts, loss_sum);
    finalize_kernel<<<1, 256, 0, stream>>>(counts, loss_sum, out);
}

// Round 10
// 270.924 us; speedup vs baseline: 1.5621x; 1.0356x over previous
//
#include <hip/hip_runtime.h>
#include <hip/hip_fp16.h>
#include <stdint.h>

// VQ-VAE forward on MI355X — fp16-MFMA fast path + fp64 rescue for exact np argmin.
// Round 18: rescue restructured 256->512 threads, 2 codes x 4 rows per thread.
// Round-17 counters: rescue=56.6us, VGPR=60 — the depth-8 ev[8] float4 batch
// (32 VGPR) + acc (32 VGPR) exceeded the compiler's chosen budget, so the load
// batch was split and the 32-iteration serial chain (L2 latency + 512cy wave
// fp64 FMA) stayed exposed; one group per block => duration == group latency.
// New shape: acc = 8 doubles (16 VGPR) + ev[8] float2 (16 VGPR) fits fully;
// per-iter VALU halves to 256cy/wave; 8 waves/block adds TLP. Per-(code,row)
// fp64 add order still ascending-d -> bit-identical rescue results.
// Everything else unchanged from round 17 (280.6us, passed).
//
// z_e: [64, 256, 32, 32] f32 ; emb: [1024, 256] f32
// out: z_q_st (16777216) | loss (1) | perplexity (1) | idx (65536, as float)
//
// Big scratch in d_out's z_q region (overwritten by epilogue last):
//   out bytes [0, 32MB)       A_hi  fp16[65536][256]  (transposed z_e, x16)
// ws layout (bytes):
//   [0,      4096)    enorm f32[1024]      [4096,   266240)  xnorm f32[65536]
//   [266240, 528384)  fidx  i32[65536]     [528384, 532480)  counts i32[1024]
//   [532480, 532484)  loss_sum             [532484, 532488)  amb_count
//   [532488, 794632)  amb i32[65536]
//   [794752, 1319040) B_hi fp16[1024][256] (e*4096)
//   [1319040,2367616) embT f32[256][1024]

#define D_DIM   256
#define K_CODES 1024
#define N_ROWS  65536
#define N_ELEM  16777216
#define IDX_OFF 16777218
#define FLAG_MARGIN 1.5e-4f
#define AMB_CAP 65536
#define A_SCALE 16.0f
#define B_SCALE 4096.0f
#define INV_SCALE2 3.0517578125e-05f   /* 2 / (16*4096) = 2^-15, exact */

typedef short short8 __attribute__((ext_vector_type(8)));
typedef _Float16 half8 __attribute__((ext_vector_type(8)));
typedef float f32x4  __attribute__((ext_vector_type(4)));

__device__ __forceinline__ unsigned int mono(float s) {
    unsigned int u = __float_as_uint(s);
    return (u & 0x80000000u) ? ~u : (u | 0x80000000u);
}
__device__ __forceinline__ float unmono(unsigned int u) {
    return __uint_as_float((u & 0x80000000u) ? (u & 0x7FFFFFFFu) : ~u);
}
__device__ __forceinline__ unsigned short f16_rne(float x) {
    return __half_as_ushort(__float2half(x));   // RNE
}
__device__ __forceinline__ void gld16(const void* g, void* l) {
    __builtin_amdgcn_global_load_lds(
        (const __attribute__((address_space(1))) unsigned int*)g,
        (__attribute__((address_space(3))) unsigned int*)l, 16, 0, 0);
}

// ---- fused prep: blocks 0-3 = emb path (enorm/B_hi/embT + zero counters);
//      blocks 4..2051 = z_e transpose -> A_hi fp16(x16) + xnorm ----
__launch_bounds__(256)
__global__ void prep_kernel(const float* __restrict__ z_e,
                            const float* __restrict__ emb,
                            unsigned short* __restrict__ A_hi,
                            float* __restrict__ xnorm,
                            float* __restrict__ enorm,
                            unsigned short* __restrict__ B_hi,
                            float* __restrict__ embT,
                            int* __restrict__ counts,
                            float* __restrict__ loss_sum,
                            int* __restrict__ amb_count) {
#pragma clang fp contract(off)
    __shared__ float T[32][257];
    __shared__ float H[32][2];
    const int bid = blockIdx.x;
    const int tid = threadIdx.x;

    if (bid < 4) {
        // emb path: one code per thread; rows register-batched as float4 for ILP.
        const int k = bid * 256 + tid;
        counts[k] = 0;
        if (bid == 0 && tid == 0) { *loss_sum = 0.f; *amb_count = 0; }
        const float* p = emb + (size_t)k * D_DIM;
        unsigned int* dstB = (unsigned int*)(B_hi + (size_t)k * D_DIM);
        float halfv[2];
        #pragma unroll
        for (int h = 0; h < 2; ++h) {
            float r[8];
            #pragma unroll
            for (int qq = 0; qq < 2; ++qq) {
                const float* qb = p + h * 128 + qq * 64;
                float4 ev[16];
                #pragma unroll
                for (int m = 0; m < 16; ++m)
                    ev[m] = *(const float4*)(qb + 4 * m);
                // np-pairwise partials: r[j] accumulated over ascending i blocks.
                #pragma unroll
                for (int t = 0; t < 8; ++t) {
                    const float4 a = ev[2 * t], b = ev[2 * t + 1];
                    if (qq == 0 && t == 0) {
                        r[0] = a.x * a.x; r[1] = a.y * a.y; r[2] = a.z * a.z; r[3] = a.w * a.w;
                        r[4] = b.x * b.x; r[5] = b.y * b.y; r[6] = b.z * b.z; r[7] = b.w * b.w;
                    } else {
                        r[0] += a.x * a.x; r[1] += a.y * a.y; r[2] += a.z * a.z; r[3] += a.w * a.w;
                        r[4] += b.x * b.x; r[5] += b.y * b.y; r[6] += b.z * b.z; r[7] += b.w * b.w;
                    }
                }
                // B_hi: sequential-d fp16(x4096) packing, 8 floats per uint4 store.
                #pragma unroll
                for (int m = 0; m < 16; m += 2) {
                    const float4 a = ev[m], b = ev[m + 1];
                    unsigned int u0 = f16_rne(a.x * B_SCALE) | ((unsigned int)f16_rne(a.y * B_SCALE) << 16);
                    unsigned int u1 = f16_rne(a.z * B_SCALE) | ((unsigned int)f16_rne(a.w * B_SCALE) << 16);
                    unsigned int u2 = f16_rne(b.x * B_SCALE) | ((unsigned int)f16_rne(b.y * B_SCALE) << 16);
                    unsigned int u3 = f16_rne(b.z * B_SCALE) | ((unsigned int)f16_rne(b.w * B_SCALE) << 16);
                    *(uint4*)(dstB + (h * 64 + qq * 32 + 2 * m)) = make_uint4(u0, u1, u2, u3);
                }
                // embT: per-lane k, fixed d per store -> coalesced across lanes.
                const int dbase = h * 128 + qq * 64;
                #pragma unroll
                for (int m = 0; m < 16; ++m) {
                    embT[(size_t)(dbase + 4 * m + 0) * K_CODES + k] = ev[m].x;
                    embT[(size_t)(dbase + 4 * m + 1) * K_CODES + k] = ev[m].y;
                    embT[(size_t)(dbase + 4 * m + 2) * K_CODES + k] = ev[m].z;
                    embT[(size_t)(dbase + 4 * m + 3) * K_CODES + k] = ev[m].w;
                }
            }
            halfv[h] = ((r[0] + r[1]) + (r[2] + r[3])) + ((r[4] + r[5]) + (r[6] + r[7]));
        }
        enorm[k] = halfv[0] + halfv[1];
        return;
    }

    // a path: transpose one [32 hw x 256 d] tile of z_e.
    const int bx = bid - 4;                    // 2048 tiles
    const int b = bx >> 5, hw0 = (bx & 31) << 5;
    const float* zb = z_e + (size_t)b * 262144 + hw0;
    #pragma unroll 4
    for (int it = 0; it < 8; ++it) {
        int flat = it * 256 + tid;             // 2048 float4
        int d = flat >> 3;
        int hw4 = (flat & 7) << 2;
        float4 v = *(const float4*)(zb + (size_t)d * 1024 + hw4);
        T[hw4 + 0][d] = v.x; T[hw4 + 1][d] = v.y;
        T[hw4 + 2][d] = v.z; T[hw4 + 3][d] = v.w;
    }
    __syncthreads();
    if (tid < 64) {                            // np pairwise tree per 128-half
        int row = tid >> 1, h = tid & 1;
        const float* q = &T[row][h * 128];
        float r[8];
        #pragma unroll
        for (int j = 0; j < 8; ++j) { float x = q[j]; r[j] = x * x; }
        for (int i = 8; i < 128; i += 8)
            #pragma unroll
            for (int j = 0; j < 8; ++j) { float x = q[i + j]; r[j] = r[j] + x * x; }
        H[row][h] = ((r[0] + r[1]) + (r[2] + r[3])) + ((r[4] + r[5]) + (r[6] + r[7]));
    }
    __syncthreads();
    if (tid < 32) xnorm[b * 1024 + hw0 + tid] = H[tid][0] + H[tid][1];
    {   // fp16(x16) convert: thread -> (row, 32-d segment)
        int row = tid >> 3, seg8 = tid & 7;
        const float* src = &T[row][seg8 * 32];
        unsigned short* dst = A_hi + ((size_t)(b * 1024 + hw0 + row) * 256 + seg8 * 32);
        #pragma unroll
        for (int c = 0; c < 4; ++c) {
            unsigned int ub[4];
            #pragma unroll
            for (int p = 0; p < 4; ++p) {
                unsigned int lo = f16_rne(src[c * 8 + 2 * p] * A_SCALE);
                unsigned int hi = f16_rne(src[c * 8 + 2 * p + 1] * A_SCALE);
                ub[p] = lo | (hi << 16);
            }
            *(uint4*)(dst + c * 8) = make_uint4(ub[0], ub[1], ub[2], ub[3]);
        }
    }
}

// ---- dist2: fp16 MFMA, 128 rows x ALL 1024 codes per block ----
// B reg-staged (depth 2), raw s_barrier + lgkmcnt(0) only: the compiler emits
// counted vmcnt waits for the reg loads, so prefetches remain in flight across
// barriers (no per-step vmcnt(0) drain). Step t: issue chunk t+2 into regs;
// ds_read + 16 MFMA on chunk t from buf[t&1]; ds_write chunk t+1 into the
// other buffer; lgkmcnt(0); s_barrier. sched_barrier(0) pins region order.
#define DSTEP(T, CUR, W0, W1, I0, I1)                                                   \
  {                                                                                     \
    const int t_ = (T);                                                                 \
    if (t_ + 2 < 64) {                                                                  \
      const int nc_ = (t_ + 2) >> 3, ns_ = (t_ + 2) & 7;                                \
      I0 = *(const uint4*)(B_hi + (((size_t)(nc_ * 128 + arsub)) << 8) + ns_ * 32 + aq);      \
      I1 = *(const uint4*)(B_hi + (((size_t)(nc_ * 128 + 64 + arsub)) << 8) + ns_ * 32 + aq); \
    }                                                                                   \
    __builtin_amdgcn_sched_barrier(0);                                                  \
    const char* bb_ = smem + 65536 + ((CUR) << 13);                                     \
    const int sv_ = t_ & 7;                                                             \
    half8 af[4], bf[4];                                                                 \
    _Pragma("unroll") for (int i = 0; i < 4; ++i)                                       \
      af[i] = *(const half8*)(smem + sv_ * 8192 + (wr * 64 + i * 16 + l16) * 64 + rdoff); \
    _Pragma("unroll") for (int j = 0; j < 4; ++j)                                       \
      bf[j] = *(const half8*)(bb_ + (wc * 64 + j * 16 + l16) * 64 + rdoff);             \
    __builtin_amdgcn_s_setprio(1);                                                      \
    _Pragma("unroll") for (int i = 0; i < 4; ++i)                                       \
      _Pragma("unroll") for (int j = 0; j < 4; ++j)                                     \
        acc[i][j] = __builtin_amdgcn_mfma_f32_16x16x32_f16(af[i], bf[j], acc[i][j], 0, 0, 0); \
    __builtin_amdgcn_s_setprio(0);                                                      \
    __builtin_amdgcn_sched_barrier(0);                                                  \
    if (t_ + 1 < 64) {                                                                  \
      char* nb_ = smem + 65536 + ((1 ^ (CUR)) << 13) + w * 1024 + (lane << 4);          \
      *(uint4*)nb_ = W0;                                                                \
      *(uint4*)(nb_ + 4096) = W1;                                                       \
    }                                                                                   \
    asm volatile("s_waitcnt lgkmcnt(0)" ::: "memory");                                  \
    __builtin_amdgcn_s_barrier();                                                       \
    __builtin_amdgcn_sched_barrier(0);                                                  \
  }

__launch_bounds__(256, 2)
__global__ void dist2_kernel(const unsigned short* __restrict__ A_hi,
                             const unsigned short* __restrict__ B_hi,
                             const float* __restrict__ xnorm,
                             const float* __restrict__ enorm,
                             int* __restrict__ fidx,
                             int* __restrict__ amb,
                             int* __restrict__ amb_count) {
    __shared__ __align__(16) char smem[81920];            // As 64KB | Bs 2x8KB
    unsigned long long* red = (unsigned long long*)(smem + 65536); // overlay buf0

    const int tid  = threadIdx.x;
    const int w = tid >> 6, lane = tid & 63;
    const int l16 = lane & 15, quad = lane >> 4;
    const int wc = w & 1, wr = w >> 1;
    const int row0 = blockIdx.x * 128;

    // staging constants: lane -> (row = base + lane/4, granule lane&3), global
    // source pre-swizzled (inverse of the read swizzle; involution).
    const int aq    = (((lane & 3) ^ ((lane >> 3) & 3)) << 3);  // shorts
    const int arsub = (w << 4) + (lane >> 2);
    // read-side swizzle: granule (quad ^ ((l16>>1)&3)) of the fragment row
    const int rdoff = ((quad ^ ((l16 >> 1) & 3)) << 4);         // bytes

    // prologue: A tile (64KB) via gld16; B chunks 0,1 into regs.
    #pragma unroll
    for (int t = 0; t < 16; ++t) {
        const int arow = ((t & 1) << 6) + arsub;
        const int s    = t >> 1;
        gld16(A_hi + (((size_t)(row0 + arow)) << 8) + s * 32 + aq,
              smem + t * 4096 + w * 1024);
    }
    uint4 p0, p1, q0, q1;
    p0 = *(const uint4*)(B_hi + (((size_t)(arsub)) << 8) + aq);              // chunk 0
    p1 = *(const uint4*)(B_hi + (((size_t)(64 + arsub)) << 8) + aq);
    q0 = *(const uint4*)(B_hi + (((size_t)(arsub)) << 8) + 32 + aq);         // chunk 1
    q1 = *(const uint4*)(B_hi + (((size_t)(64 + arsub)) << 8) + 32 + aq);
    {   // ds_write chunk 0 -> buf0 (its vmcnt wait also drains the A gld16s)
        char* d0 = smem + 65536 + w * 1024 + (lane << 4);
        *(uint4*)d0 = p0;
        *(uint4*)(d0 + 4096) = p1;
    }
    asm volatile("s_waitcnt lgkmcnt(0)" ::: "memory");
    __builtin_amdgcn_s_barrier();
    __builtin_amdgcn_sched_barrier(0);

    // per-thread state
    float xnr[4][4];
    #pragma unroll
    for (int i = 0; i < 4; ++i)
        #pragma unroll
        for (int r = 0; r < 4; ++r)
            xnr[i][r] = xnorm[row0 + wr * 64 + i * 16 + quad * 4 + r];

    const float INF = __uint_as_float(0x7F800000u);
    float m1[4][4], m2[4][4];
    unsigned int ix[4][4];
    #pragma unroll
    for (int i = 0; i < 4; ++i)
        #pragma unroll
        for (int r = 0; r < 4; ++r) { m1[i][r] = INF; m2[i][r] = INF; ix[i][r] = 0u; }

    // main loop: 8 code-chunks x 8 K-steps, 2-step unrolled for buffer parity.
    for (int cb = 0; cb < 8; ++cb) {
        f32x4 acc[4][4];
        #pragma unroll
        for (int i = 0; i < 4; ++i)
            #pragma unroll
            for (int j = 0; j < 4; ++j) acc[i][j] = (f32x4){0.f, 0.f, 0.f, 0.f};

        #pragma unroll
        for (int sh = 0; sh < 4; ++sh) {
            DSTEP(cb * 8 + 2 * sh,     0, q0, q1, p0, p1);   // even: buf0; write q; issue p
            DSTEP(cb * 8 + 2 * sh + 1, 1, p0, p1, q0, q1);   // odd:  buf1; write p; issue q
        }

        // fold chunk into running float top-2 + argmin idx.
        float enj[4];
        #pragma unroll
        for (int j = 0; j < 4; ++j) enj[j] = enorm[cb * 128 + wc * 64 + j * 16 + l16];
        #pragma unroll
        for (int i = 0; i < 4; ++i) {
            #pragma unroll
            for (int r = 0; r < 4; ++r) {
                const float xn = xnr[i][r];
                float a = m1[i][r], b = m2[i][r];
                unsigned int id = ix[i][r];
                #pragma unroll
                for (int j = 0; j < 4; ++j) {
                    const unsigned int n = cb * 128 + wc * 64 + j * 16 + l16;
                    float sc = fmaf(acc[i][j][r], -INV_SCALE2, xn + enj[j]);
                    bool c = sc < a;
                    b = fminf(b, fmaxf(a, sc));
                    a = fminf(a, sc);
                    id = c ? n : id;
                }
                m1[i][r] = a; m2[i][r] = b; ix[i][r] = id;
            }
        }
    }

    // one reduce per row: u64 pack now, 16-lane shfl tree, wc-pair merge in LDS.
    #pragma unroll
    for (int i = 0; i < 4; ++i) {
        #pragma unroll
        for (int r = 0; r < 4; ++r) {
            unsigned long long a1 = ((unsigned long long)mono(m1[i][r]) << 32) | ix[i][r];
            unsigned long long a2 = ((unsigned long long)mono(m2[i][r]) << 32) | 0xFFFFFFFFull;
            #pragma unroll
            for (int m = 1; m < 16; m <<= 1) {
                unsigned long long u1 = __shfl_xor(a1, m, 16);
                unsigned long long u2 = __shfl_xor(a2, m, 16);
                if (u1 < a1) { a2 = (a1 < u2) ? a1 : u2; a1 = u1; }
                else         { a2 = (a2 < u1) ? a2 : u1; }
            }
            if (l16 == 0) {
                int rowl = wr * 64 + i * 16 + quad * 4 + r;
                red[(rowl * 2 + wc) * 2 + 0] = a1;
                red[(rowl * 2 + wc) * 2 + 1] = a2;
            }
        }
    }
    __syncthreads();
    if (tid < 128) {
        unsigned long long a1 = red[(tid * 2 + 0) * 2 + 0];
        unsigned long long a2 = red[(tid * 2 + 0) * 2 + 1];
        unsigned long long b1 = red[(tid * 2 + 1) * 2 + 0];
        unsigned long long b2 = red[(tid * 2 + 1) * 2 + 1];
        if (b1 < a1) { a2 = (a1 < b2) ? a1 : b2; a1 = b1; }
        else         { a2 = (a2 < b1) ? a2 : b1; }
        const int row = row0 + tid;
        fidx[row] = (int)(a1 & 0xFFFFFFFFull);
        float s1 = unmono((unsigned int)(a1 >> 32));
        float s2 = unmono((unsigned int)(a2 >> 32));
        if (s2 - s1 <= FLAG_MARGIN) {
            int slot = atomicAdd(amb_count, 1);
            if (slot < AMB_CAP) amb[slot] = row;
        }
    }
}

// ---- rescue (4 rows/group, 512 threads): thread owns 2 consecutive codes x
// 4 rows. acc = 8 doubles (16 VGPR) + ev[8] float2 (16 VGPR) -> the depth-8
// batch actually fits in registers (round-17: VGPR=60 forced batch split).
// Per-(code,row) fp64 add order still ascending d -> bit-identical results.
__launch_bounds__(512)
__global__ void rescue4_kernel(const float* __restrict__ z_e,
                               const float* __restrict__ embT,
                               const float* __restrict__ xnorm,
                               const float* __restrict__ enorm,
                               const int* __restrict__ amb,
                               const int* __restrict__ amb_count,
                               int* __restrict__ fidx) {
    __shared__ float xs[4][256];
    __shared__ int rows[4];
    __shared__ unsigned long long pm[4][513];
    const int tid = threadIdx.x;
    int cnt = *amb_count;
    if (cnt > AMB_CAP) cnt = AMB_CAP;
    if (cnt <= 0) return;
    const int ngroups = (cnt + 3) >> 2;
    for (int g = blockIdx.x; g < ngroups; g += gridDim.x) {
        if (tid < 4) {
            int e = g * 4 + tid;
            rows[tid] = amb[e < cnt ? e : (cnt - 1)];   // pad with dup (benign)
        }
        __syncthreads();
        {   // stage x rows: thread -> (row j = tid>>7, 2 d-elements)
            const int j = tid >> 7, d0 = (tid & 127) * 2;
            const int row = rows[j];
            const int b = row >> 10, hw = row & 1023;
            const float* zp = z_e + (size_t)b * 262144 + hw;
            xs[j][d0 + 0] = zp[(size_t)(d0 + 0) * 1024];
            xs[j][d0 + 1] = zp[(size_t)(d0 + 1) * 1024];
        }
        __syncthreads();

        double acc[2][4];                       // [code c][row j], static idx only
        #pragma unroll
        for (int c = 0; c < 2; ++c)
            #pragma unroll
            for (int j = 0; j < 4; ++j) acc[c][j] = 0.0;

        const float* ep = embT + 2 * tid;
        for (int d0 = 0; d0 < D_DIM; d0 += 8) {
            float2 ev[8];
            #pragma unroll
            for (int u = 0; u < 8; ++u)
                ev[u] = *(const float2*)(ep + (size_t)(d0 + u) * K_CODES);
            #pragma unroll
            for (int u = 0; u < 8; ++u) {
                const int d = d0 + u;
                double e0 = (double)ev[u].x, e1 = (double)ev[u].y;
                double x0 = (double)xs[0][d], x1 = (double)xs[1][d];
                double x2 = (double)xs[2][d], x3 = (double)xs[3][d];
                acc[0][0] += x0 * e0; acc[0][1] += x1 * e0; acc[0][2] += x2 * e0; acc[0][3] += x3 * e0;
                acc[1][0] += x0 * e1; acc[1][1] += x1 * e1; acc[1][2] += x2 * e1; acc[1][3] += x3 * e1;
            }
        }

        float xnr[4];
        #pragma unroll
        for (int j = 0; j < 4; ++j) xnr[j] = xnorm[rows[j]];

        unsigned long long mm[4] = {~0ull, ~0ull, ~0ull, ~0ull};
        #pragma unroll
        for (int c = 0; c < 2; ++c) {
            const int k = 2 * tid + c;
            const float en = enorm[k];
            #pragma unroll
            for (int j = 0; j < 4; ++j) {
                float dv = (float)acc[c][j];
                float t = xnr[j] + en;
                float s = t - 2.f * dv;
                unsigned long long p = ((unsigned long long)mono(s) << 32) | (unsigned int)k;
                if (p < mm[j]) mm[j] = p;
            }
        }
        #pragma unroll
        for (int j = 0; j < 4; ++j) pm[j][tid] = mm[j];
        __syncthreads();
        for (int s = 256; s > 0; s >>= 1) {
            if (tid < s) {
                #pragma unroll
                for (int j = 0; j < 4; ++j)
                    if (pm[j][tid + s] < pm[j][tid]) pm[j][tid] = pm[j][tid + s];
            }
            __syncthreads();
        }
        if (tid < 4) fidx[rows[tid]] = (int)(pm[tid][0] & 0xFFFFFFFFull);
        __syncthreads();
    }
}

// ---- epilogue: hw-vectorized (16B/lane); no fences (round-16 lesson) ----
__global__ void epilogue_kernel(const float* __restrict__ z_e,
                                const float* __restrict__ emb,
                                const int* __restrict__ fidx,
                                float* __restrict__ out,
                                int* __restrict__ counts,
                                float* __restrict__ loss_sum) {
    __shared__ int   kb[64];
    __shared__ float rs[256];
    const int tid = threadIdx.x;
    const int rcb = blockIdx.x;
    const int b   = rcb >> 4;
    const int hw0 = (rcb & 15) << 6;

    if (tid < 64) {
        int k = fidx[rcb * 64 + tid];
        kb[tid] = k;
        out[(size_t)IDX_OFF + (size_t)rcb * 64 + tid] = (float)k;
        atomicAdd(&counts[k], 1);
    }
    __syncthreads();

    const int j4 = (tid & 15) << 2;   // hw offset within the 64-chunk, float4
    const int dq = tid >> 4;          // 16 d-slices
    const float* e0 = emb + (size_t)kb[j4 + 0] * D_DIM;
    const float* e1 = emb + (size_t)kb[j4 + 1] * D_DIM;
    const float* e2 = emb + (size_t)kb[j4 + 2] * D_DIM;
    const float* e3 = emb + (size_t)kb[j4 + 3] * D_DIM;
    const size_t base = (size_t)b * 262144 + hw0 + j4;
    float ls = 0.f;
    #pragma unroll 4
    for (int d = dq; d < D_DIM; d += 16) {
        size_t off = base + ((size_t)d << 10);
        float4 x = *(const float4*)(z_e + off);
        float4 q;
        q.x = e0[d]; q.y = e1[d]; q.z = e2[d]; q.w = e3[d];
        *(float4*)(out + off) = q;
        float d0 = q.x - x.x, d1 = q.y - x.y, d2 = q.z - x.z, d3 = q.w - x.w;
        ls += d0 * d0; ls += d1 * d1; ls += d2 * d2; ls += d3 * d3;
    }
    rs[tid] = ls;
    __syncthreads();
    for (int s = 128; s > 0; s >>= 1) {
        if (tid < s) rs[tid] += rs[tid + s];
        __syncthreads();
    }
    if (tid == 0) atomicAdd(loss_sum, rs[0]);
}

__global__ void finalize_kernel(const int* __restrict__ counts,
                                const float* __restrict__ loss_sum,
                                float* __restrict__ out) {
    __shared__ float rs[256];
    const int tid = threadIdx.x;
    float s = 0.f;
    for (int k = tid; k < K_CODES; k += 256) {
        float p = (float)counts[k] / 65536.0f;
        s += p * logf(p + 1e-10f);
    }
    rs[tid] = s;
    __syncthreads();
    for (int st = 128; st > 0; st >>= 1) {
        if (tid < st) rs[tid] += rs[tid + st];
        __syncthreads();
    }
    if (tid == 0) {
        out[N_ELEM]     = loss_sum[0] * 1.25f / 16777216.0f;
        out[N_ELEM + 1] = expf(-rs[0]);
    }
}

extern "C" void kernel_launch(void* const* d_in, const int* in_sizes, int n_in,
                              void* d_out, int out_size, void* d_ws, size_t ws_size,
                              hipStream_t stream) {
    const float* z_e = (const float*)d_in[0];
    const float* emb = (const float*)d_in[1];
    float* out = (float*)d_out;
    char*  ws  = (char*)d_ws;

    // big scratch inside d_out (overwritten by epilogue)
    unsigned short* A_hi = (unsigned short*)d_out;

    float*          enorm    = (float*)ws;
    float*          xnorm    = (float*)(ws + 4096);
    int*            fidx     = (int*)(ws + 266240);
    int*            counts   = (int*)(ws + 528384);
    float*          loss_sum = (float*)(ws + 532480);
    int*            amb_cnt  = (int*)(ws + 532484);
    int*            amb      = (int*)(ws + 532488);
    unsigned short* B_hi     = (unsigned short*)(ws + 794752);
    float*          embT     = (float*)(ws + 1319040);

    prep_kernel<<<2052, 256, 0, stream>>>(z_e, emb, A_hi, xnorm, enorm, B_hi, embT,
                                          counts, loss_sum, amb_cnt);
    dist2_kernel<<<512, 256, 0, stream>>>(A_hi, B_hi, xnorm, enorm, fidx, amb, amb_cnt);
    rescue4_kernel<<<1024, 512, 0, stream>>>(z_e, embT, xnorm, enorm, amb, amb_cnt, fidx);
    epilogue_kernel<<<N_ROWS / 64, 256, 0, stream>>>(z_e, emb, fidx, out, counts, loss_sum);
    finalize_kernel<<<1, 256, 0, stream>>>(counts, loss_sum, out);
}

// Round 11
// 259.579 us; speedup vs baseline: 1.6303x; 1.0437x over previous
//
#include <hip/hip_runtime.h>
#include <hip/hip_fp16.h>
#include <stdint.h>

// VQ-VAE forward on MI355X — fp16-MFMA fast path + fp64 rescue for exact np argmin.
// Round 19: (1) dist2 schedule UNPINNED: removed the 3 sched_barrier(0)/step
// (192 fences — m141: order-pinning defeats compiler scheduling) and setprio
// (m190: ~0 on non-8-phase). Raw s_barrier + asm lgkmcnt(0) kept (required);
// vmcnt stays counted on the reg prefetches. rule-18 hazard absent: no reg-only
// op reads a ds_read dest across the wait; s_barrier has side effects so LDS ops
// can't cross. (2) fast-path score drops xnorm (per-row constant -> argmin
// unchanged in exact arithmetic; any row where fp32 t-order could differ from
// s-order has gap <=~3e-5 << margin -> flagged -> rescued exactly; rescue still
// includes xnorm, bit-identical to np). Frees xnr regs + 1 VALU/candidate.
// (3) epilogue: 64 emb rows staged to LDS once (coalesced 1KB-row loads,
// stride-257 pad -> 2-way-free reads) replacing 64 scalar L2 gathers/thread;
// values bit-identical. Round-18: 270.9us; dist2=55 top; ~216us profiling-blind.
//
// z_e: [64, 256, 32, 32] f32 ; emb: [1024, 256] f32
// out: z_q_st (16777216) | loss (1) | perplexity (1) | idx (65536, as float)
//
// Big scratch in d_out's z_q region (overwritten by epilogue last):
//   out bytes [0, 32MB)       A_hi  fp16[65536][256]  (transposed z_e, x16)
// ws layout (bytes):
//   [0,      4096)    enorm f32[1024]      [4096,   266240)  xnorm f32[65536]
//   [266240, 528384)  fidx  i32[65536]     [528384, 532480)  counts i32[1024]
//   [532480, 532484)  loss_sum             [532484, 532488)  amb_count
//   [532488, 794632)  amb i32[65536]
//   [794752, 1319040) B_hi fp16[1024][256] (e*4096)
//   [1319040,2367616) embT f32[256][1024]

#define D_DIM   256
#define K_CODES 1024
#define N_ROWS  65536
#define N_ELEM  16777216
#define IDX_OFF 16777218
#define FLAG_MARGIN 1.5e-4f
#define AMB_CAP 65536
#define A_SCALE 16.0f
#define B_SCALE 4096.0f
#define INV_SCALE2 3.0517578125e-05f   /* 2 / (16*4096) = 2^-15, exact */

typedef short short8 __attribute__((ext_vector_type(8)));
typedef _Float16 half8 __attribute__((ext_vector_type(8)));
typedef float f32x4  __attribute__((ext_vector_type(4)));

__device__ __forceinline__ unsigned int mono(float s) {
    unsigned int u = __float_as_uint(s);
    return (u & 0x80000000u) ? ~u : (u | 0x80000000u);
}
__device__ __forceinline__ float unmono(unsigned int u) {
    return __uint_as_float((u & 0x80000000u) ? (u & 0x7FFFFFFFu) : ~u);
}
__device__ __forceinline__ unsigned short f16_rne(float x) {
    return __half_as_ushort(__float2half(x));   // RNE
}
__device__ __forceinline__ void gld16(const void* g, void* l) {
    __builtin_amdgcn_global_load_lds(
        (const __attribute__((address_space(1))) unsigned int*)g,
        (__attribute__((address_space(3))) unsigned int*)l, 16, 0, 0);
}

// ---- fused prep: blocks 0-3 = emb path (enorm/B_hi/embT + zero counters);
//      blocks 4..2051 = z_e transpose -> A_hi fp16(x16) + xnorm ----
__launch_bounds__(256)
__global__ void prep_kernel(const float* __restrict__ z_e,
                            const float* __restrict__ emb,
                            unsigned short* __restrict__ A_hi,
                            float* __restrict__ xnorm,
                            float* __restrict__ enorm,
                            unsigned short* __restrict__ B_hi,
                            float* __restrict__ embT,
                            int* __restrict__ counts,
                            float* __restrict__ loss_sum,
                            int* __restrict__ amb_count) {
#pragma clang fp contract(off)
    __shared__ float T[32][257];
    __shared__ float H[32][2];
    const int bid = blockIdx.x;
    const int tid = threadIdx.x;

    if (bid < 4) {
        // emb path: one code per thread; rows register-batched as float4 for ILP.
        const int k = bid * 256 + tid;
        counts[k] = 0;
        if (bid == 0 && tid == 0) { *loss_sum = 0.f; *amb_count = 0; }
        const float* p = emb + (size_t)k * D_DIM;
        unsigned int* dstB = (unsigned int*)(B_hi + (size_t)k * D_DIM);
        float halfv[2];
        #pragma unroll
        for (int h = 0; h < 2; ++h) {
            float r[8];
            #pragma unroll
            for (int qq = 0; qq < 2; ++qq) {
                const float* qb = p + h * 128 + qq * 64;
                float4 ev[16];
                #pragma unroll
                for (int m = 0; m < 16; ++m)
                    ev[m] = *(const float4*)(qb + 4 * m);
                // np-pairwise partials: r[j] accumulated over ascending i blocks.
                #pragma unroll
                for (int t = 0; t < 8; ++t) {
                    const float4 a = ev[2 * t], b = ev[2 * t + 1];
                    if (qq == 0 && t == 0) {
                        r[0] = a.x * a.x; r[1] = a.y * a.y; r[2] = a.z * a.z; r[3] = a.w * a.w;
                        r[4] = b.x * b.x; r[5] = b.y * b.y; r[6] = b.z * b.z; r[7] = b.w * b.w;
                    } else {
                        r[0] += a.x * a.x; r[1] += a.y * a.y; r[2] += a.z * a.z; r[3] += a.w * a.w;
                        r[4] += b.x * b.x; r[5] += b.y * b.y; r[6] += b.z * b.z; r[7] += b.w * b.w;
                    }
                }
                // B_hi: sequential-d fp16(x4096) packing, 8 floats per uint4 store.
                #pragma unroll
                for (int m = 0; m < 16; m += 2) {
                    const float4 a = ev[m], b = ev[m + 1];
                    unsigned int u0 = f16_rne(a.x * B_SCALE) | ((unsigned int)f16_rne(a.y * B_SCALE) << 16);
                    unsigned int u1 = f16_rne(a.z * B_SCALE) | ((unsigned int)f16_rne(a.w * B_SCALE) << 16);
                    unsigned int u2 = f16_rne(b.x * B_SCALE) | ((unsigned int)f16_rne(b.y * B_SCALE) << 16);
                    unsigned int u3 = f16_rne(b.z * B_SCALE) | ((unsigned int)f16_rne(b.w * B_SCALE) << 16);
                    *(uint4*)(dstB + (h * 64 + qq * 32 + 2 * m)) = make_uint4(u0, u1, u2, u3);
                }
                // embT: per-lane k, fixed d per store -> coalesced across lanes.
                const int dbase = h * 128 + qq * 64;
                #pragma unroll
                for (int m = 0; m < 16; ++m) {
                    embT[(size_t)(dbase + 4 * m + 0) * K_CODES + k] = ev[m].x;
                    embT[(size_t)(dbase + 4 * m + 1) * K_CODES + k] = ev[m].y;
                    embT[(size_t)(dbase + 4 * m + 2) * K_CODES + k] = ev[m].z;
                    embT[(size_t)(dbase + 4 * m + 3) * K_CODES + k] = ev[m].w;
                }
            }
            halfv[h] = ((r[0] + r[1]) + (r[2] + r[3])) + ((r[4] + r[5]) + (r[6] + r[7]));
        }
        enorm[k] = halfv[0] + halfv[1];
        return;
    }

    // a path: transpose one [32 hw x 256 d] tile of z_e.
    const int bx = bid - 4;                    // 2048 tiles
    const int b = bx >> 5, hw0 = (bx & 31) << 5;
    const float* zb = z_e + (size_t)b * 262144 + hw0;
    #pragma unroll 4
    for (int it = 0; it < 8; ++it) {
        int flat = it * 256 + tid;             // 2048 float4
        int d = flat >> 3;
        int hw4 = (flat & 7) << 2;
        float4 v = *(const float4*)(zb + (size_t)d * 1024 + hw4);
        T[hw4 + 0][d] = v.x; T[hw4 + 1][d] = v.y;
        T[hw4 + 2][d] = v.z; T[hw4 + 3][d] = v.w;
    }
    __syncthreads();
    if (tid < 64) {                            // np pairwise tree per 128-half
        int row = tid >> 1, h = tid & 1;
        const float* q = &T[row][h * 128];
        float r[8];
        #pragma unroll
        for (int j = 0; j < 8; ++j) { float x = q[j]; r[j] = x * x; }
        for (int i = 8; i < 128; i += 8)
            #pragma unroll
            for (int j = 0; j < 8; ++j) { float x = q[i + j]; r[j] = r[j] + x * x; }
        H[row][h] = ((r[0] + r[1]) + (r[2] + r[3])) + ((r[4] + r[5]) + (r[6] + r[7]));
    }
    __syncthreads();
    if (tid < 32) xnorm[b * 1024 + hw0 + tid] = H[tid][0] + H[tid][1];
    {   // fp16(x16) convert: thread -> (row, 32-d segment)
        int row = tid >> 3, seg8 = tid & 7;
        const float* src = &T[row][seg8 * 32];
        unsigned short* dst = A_hi + ((size_t)(b * 1024 + hw0 + row) * 256 + seg8 * 32);
        #pragma unroll
        for (int c = 0; c < 4; ++c) {
            unsigned int ub[4];
            #pragma unroll
            for (int p = 0; p < 4; ++p) {
                unsigned int lo = f16_rne(src[c * 8 + 2 * p] * A_SCALE);
                unsigned int hi = f16_rne(src[c * 8 + 2 * p + 1] * A_SCALE);
                ub[p] = lo | (hi << 16);
            }
            *(uint4*)(dst + c * 8) = make_uint4(ub[0], ub[1], ub[2], ub[3]);
        }
    }
}

// ---- dist2: fp16 MFMA, 128 rows x ALL 1024 codes per block ----
// B reg-staged (depth 2), raw s_barrier + asm lgkmcnt(0) only; schedule left
// FREE for the compiler (no sched_barrier, no setprio — m141/m190). Fast-path
// score is t = enorm - 2*x.e (xnorm dropped: per-row constant, argmin-invariant;
// near-ties are flagged and rescued with the xnorm-inclusive exact path).
#define DSTEP(T, CUR, W0, W1, I0, I1)                                                   \
  {                                                                                     \
    const int t_ = (T);                                                                 \
    if (t_ + 2 < 64) {                                                                  \
      const int nc_ = (t_ + 2) >> 3, ns_ = (t_ + 2) & 7;                                \
      I0 = *(const uint4*)(B_hi + (((size_t)(nc_ * 128 + arsub)) << 8) + ns_ * 32 + aq);      \
      I1 = *(const uint4*)(B_hi + (((size_t)(nc_ * 128 + 64 + arsub)) << 8) + ns_ * 32 + aq); \
    }                                                                                   \
    const char* bb_ = smem + 65536 + ((CUR) << 13);                                     \
    const int sv_ = t_ & 7;                                                             \
    half8 af[4], bf[4];                                                                 \
    _Pragma("unroll") for (int i = 0; i < 4; ++i)                                       \
      af[i] = *(const half8*)(smem + sv_ * 8192 + (wr * 64 + i * 16 + l16) * 64 + rdoff); \
    _Pragma("unroll") for (int j = 0; j < 4; ++j)                                       \
      bf[j] = *(const half8*)(bb_ + (wc * 64 + j * 16 + l16) * 64 + rdoff);             \
    _Pragma("unroll") for (int i = 0; i < 4; ++i)                                       \
      _Pragma("unroll") for (int j = 0; j < 4; ++j)                                     \
        acc[i][j] = __builtin_amdgcn_mfma_f32_16x16x32_f16(af[i], bf[j], acc[i][j], 0, 0, 0); \
    if (t_ + 1 < 64) {                                                                  \
      char* nb_ = smem + 65536 + ((1 ^ (CUR)) << 13) + w * 1024 + (lane << 4);          \
      *(uint4*)nb_ = W0;                                                                \
      *(uint4*)(nb_ + 4096) = W1;                                                       \
    }                                                                                   \
    asm volatile("s_waitcnt lgkmcnt(0)" ::: "memory");                                  \
    __builtin_amdgcn_s_barrier();                                                       \
  }

__launch_bounds__(256, 2)
__global__ void dist2_kernel(const unsigned short* __restrict__ A_hi,
                             const unsigned short* __restrict__ B_hi,
                             const float* __restrict__ enorm,
                             int* __restrict__ fidx,
                             int* __restrict__ amb,
                             int* __restrict__ amb_count) {
    __shared__ __align__(16) char smem[81920];            // As 64KB | Bs 2x8KB
    unsigned long long* red = (unsigned long long*)(smem + 65536); // overlay buf0

    const int tid  = threadIdx.x;
    const int w = tid >> 6, lane = tid & 63;
    const int l16 = lane & 15, quad = lane >> 4;
    const int wc = w & 1, wr = w >> 1;
    const int row0 = blockIdx.x * 128;

    // staging constants: lane -> (row = base + lane/4, granule lane&3), global
    // source pre-swizzled (inverse of the read swizzle; involution).
    const int aq    = (((lane & 3) ^ ((lane >> 3) & 3)) << 3);  // shorts
    const int arsub = (w << 4) + (lane >> 2);
    // read-side swizzle: granule (quad ^ ((l16>>1)&3)) of the fragment row
    const int rdoff = ((quad ^ ((l16 >> 1) & 3)) << 4);         // bytes

    // prologue: A tile (64KB) via gld16; B chunks 0,1 into regs.
    #pragma unroll
    for (int t = 0; t < 16; ++t) {
        const int arow = ((t & 1) << 6) + arsub;
        const int s    = t >> 1;
        gld16(A_hi + (((size_t)(row0 + arow)) << 8) + s * 32 + aq,
              smem + t * 4096 + w * 1024);
    }
    uint4 p0, p1, q0, q1;
    p0 = *(const uint4*)(B_hi + (((size_t)(arsub)) << 8) + aq);              // chunk 0
    p1 = *(const uint4*)(B_hi + (((size_t)(64 + arsub)) << 8) + aq);
    q0 = *(const uint4*)(B_hi + (((size_t)(arsub)) << 8) + 32 + aq);         // chunk 1
    q1 = *(const uint4*)(B_hi + (((size_t)(64 + arsub)) << 8) + 32 + aq);
    {   // ds_write chunk 0 -> buf0 (its vmcnt wait also drains the A gld16s)
        char* d0 = smem + 65536 + w * 1024 + (lane << 4);
        *(uint4*)d0 = p0;
        *(uint4*)(d0 + 4096) = p1;
    }
    asm volatile("s_waitcnt lgkmcnt(0)" ::: "memory");
    __builtin_amdgcn_s_barrier();

    const float INF = __uint_as_float(0x7F800000u);
    float m1[4][4], m2[4][4];
    unsigned int ix[4][4];
    #pragma unroll
    for (int i = 0; i < 4; ++i)
        #pragma unroll
        for (int r = 0; r < 4; ++r) { m1[i][r] = INF; m2[i][r] = INF; ix[i][r] = 0u; }

    // main loop: 8 code-chunks x 8 K-steps, 2-step unrolled for buffer parity.
    for (int cb = 0; cb < 8; ++cb) {
        f32x4 acc[4][4];
        #pragma unroll
        for (int i = 0; i < 4; ++i)
            #pragma unroll
            for (int j = 0; j < 4; ++j) acc[i][j] = (f32x4){0.f, 0.f, 0.f, 0.f};

        #pragma unroll
        for (int sh = 0; sh < 4; ++sh) {
            DSTEP(cb * 8 + 2 * sh,     0, q0, q1, p0, p1);   // even: buf0; write q; issue p
            DSTEP(cb * 8 + 2 * sh + 1, 1, p0, p1, q0, q1);   // odd:  buf1; write p; issue q
        }

        // fold chunk into running float top-2 + argmin idx (t-space, no xnorm).
        float enj[4];
        #pragma unroll
        for (int j = 0; j < 4; ++j) enj[j] = enorm[cb * 128 + wc * 64 + j * 16 + l16];
        #pragma unroll
        for (int i = 0; i < 4; ++i) {
            #pragma unroll
            for (int r = 0; r < 4; ++r) {
                float a = m1[i][r], b = m2[i][r];
                unsigned int id = ix[i][r];
                #pragma unroll
                for (int j = 0; j < 4; ++j) {
                    const unsigned int n = cb * 128 + wc * 64 + j * 16 + l16;
                    float sc = fmaf(acc[i][j][r], -INV_SCALE2, enj[j]);
                    bool c = sc < a;
                    b = fminf(b, fmaxf(a, sc));
                    a = fminf(a, sc);
                    id = c ? n : id;
                }
                m1[i][r] = a; m2[i][r] = b; ix[i][r] = id;
            }
        }
    }

    // one reduce per row: u64 pack now, 16-lane shfl tree, wc-pair merge in LDS.
    #pragma unroll
    for (int i = 0; i < 4; ++i) {
        #pragma unroll
        for (int r = 0; r < 4; ++r) {
            unsigned long long a1 = ((unsigned long long)mono(m1[i][r]) << 32) | ix[i][r];
            unsigned long long a2 = ((unsigned long long)mono(m2[i][r]) << 32) | 0xFFFFFFFFull;
            #pragma unroll
            for (int m = 1; m < 16; m <<= 1) {
                unsigned long long u1 = __shfl_xor(a1, m, 16);
                unsigned long long u2 = __shfl_xor(a2, m, 16);
                if (u1 < a1) { a2 = (a1 < u2) ? a1 : u2; a1 = u1; }
                else         { a2 = (a2 < u1) ? a2 : u1; }
            }
            if (l16 == 0) {
                int rowl = wr * 64 + i * 16 + quad * 4 + r;
                red[(rowl * 2 + wc) * 2 + 0] = a1;
                red[(rowl * 2 + wc) * 2 + 1] = a2;
            }
        }
    }
    __syncthreads();
    if (tid < 128) {
        unsigned long long a1 = red[(tid * 2 + 0) * 2 + 0];
        unsigned long long a2 = red[(tid * 2 + 0) * 2 + 1];
        unsigned long long b1 = red[(tid * 2 + 1) * 2 + 0];
        unsigned long long b2 = red[(tid * 2 + 1) * 2 + 1];
        if (b1 < a1) { a2 = (a1 < b2) ? a1 : b2; a1 = b1; }
        else         { a2 = (a2 < b1) ? a2 : b1; }
        const int row = row0 + tid;
        fidx[row] = (int)(a1 & 0xFFFFFFFFull);
        float s1 = unmono((unsigned int)(a1 >> 32));
        float s2 = unmono((unsigned int)(a2 >> 32));
        if (s2 - s1 <= FLAG_MARGIN) {
            int slot = atomicAdd(amb_count, 1);
            if (slot < AMB_CAP) amb[slot] = row;
        }
    }
}

// ---- rescue (4 rows/group, 512 threads): thread owns 2 consecutive codes x
// 4 rows. acc = 8 doubles + ev[8] float2 fit fully in registers.
// Per-(code,row) fp64 add order still ascending d -> bit-identical results.
__launch_bounds__(512)
__global__ void rescue4_kernel(const float* __restrict__ z_e,
                               const float* __restrict__ embT,
                               const float* __restrict__ xnorm,
                               const float* __restrict__ enorm,
                               const int* __restrict__ amb,
                               const int* __restrict__ amb_count,
                               int* __restrict__ fidx) {
    __shared__ float xs[4][256];
    __shared__ int rows[4];
    __shared__ unsigned long long pm[4][513];
    const int tid = threadIdx.x;
    int cnt = *amb_count;
    if (cnt > AMB_CAP) cnt = AMB_CAP;
    if (cnt <= 0) return;
    const int ngroups = (cnt + 3) >> 2;
    for (int g = blockIdx.x; g < ngroups; g += gridDim.x) {
        if (tid < 4) {
            int e = g * 4 + tid;
            rows[tid] = amb[e < cnt ? e : (cnt - 1)];   // pad with dup (benign)
        }
        __syncthreads();
        {   // stage x rows: thread -> (row j = tid>>7, 2 d-elements)
            const int j = tid >> 7, d0 = (tid & 127) * 2;
            const int row = rows[j];
            const int b = row >> 10, hw = row & 1023;
            const float* zp = z_e + (size_t)b * 262144 + hw;
            xs[j][d0 + 0] = zp[(size_t)(d0 + 0) * 1024];
            xs[j][d0 + 1] = zp[(size_t)(d0 + 1) * 1024];
        }
        __syncthreads();

        double acc[2][4];                       // [code c][row j], static idx only
        #pragma unroll
        for (int c = 0; c < 2; ++c)
            #pragma unroll
            for (int j = 0; j < 4; ++j) acc[c][j] = 0.0;

        const float* ep = embT + 2 * tid;
        for (int d0 = 0; d0 < D_DIM; d0 += 8) {
            float2 ev[8];
            #pragma unroll
            for (int u = 0; u < 8; ++u)
                ev[u] = *(const float2*)(ep + (size_t)(d0 + u) * K_CODES);
            #pragma unroll
            for (int u = 0; u < 8; ++u) {
                const int d = d0 + u;
                double e0 = (double)ev[u].x, e1 = (double)ev[u].y;
                double x0 = (double)xs[0][d], x1 = (double)xs[1][d];
                double x2 = (double)xs[2][d], x3 = (double)xs[3][d];
                acc[0][0] += x0 * e0; acc[0][1] += x1 * e0; acc[0][2] += x2 * e0; acc[0][3] += x3 * e0;
                acc[1][0] += x0 * e1; acc[1][1] += x1 * e1; acc[1][2] += x2 * e1; acc[1][3] += x3 * e1;
            }
        }

        float xnr[4];
        #pragma unroll
        for (int j = 0; j < 4; ++j) xnr[j] = xnorm[rows[j]];

        unsigned long long mm[4] = {~0ull, ~0ull, ~0ull, ~0ull};
        #pragma unroll
        for (int c = 0; c < 2; ++c) {
            const int k = 2 * tid + c;
            const float en = enorm[k];
            #pragma unroll
            for (int j = 0; j < 4; ++j) {
                float dv = (float)acc[c][j];
                float t = xnr[j] + en;
                float s = t - 2.f * dv;
                unsigned long long p = ((unsigned long long)mono(s) << 32) | (unsigned int)k;
                if (p < mm[j]) mm[j] = p;
            }
        }
        #pragma unroll
        for (int j = 0; j < 4; ++j) pm[j][tid] = mm[j];
        __syncthreads();
        for (int s = 256; s > 0; s >>= 1) {
            if (tid < s) {
                #pragma unroll
                for (int j = 0; j < 4; ++j)
                    if (pm[j][tid + s] < pm[j][tid]) pm[j][tid] = pm[j][tid + s];
            }
            __syncthreads();
        }
        if (tid < 4) fidx[rows[tid]] = (int)(pm[tid][0] & 0xFFFFFFFFull);
        __syncthreads();
    }
}

// ---- epilogue: hw-vectorized (16B/lane); emb rows staged in LDS (replaces
// 64 scalar L2 gathers/thread with coalesced row loads + 2-way-free LDS reads).
// Values bit-identical to the gather version.
__launch_bounds__(256)
__global__ void epilogue_kernel(const float* __restrict__ z_e,
                                const float* __restrict__ emb,
                                const int* __restrict__ fidx,
                                float* __restrict__ out,
                                int* __restrict__ counts,
                                float* __restrict__ loss_sum) {
    __shared__ int   kb[64];
    __shared__ float L[64][257];
    __shared__ float rs[256];
    const int tid = threadIdx.x;
    const int rcb = blockIdx.x;
    const int b   = rcb >> 4;
    const int hw0 = (rcb & 15) << 6;

    if (tid < 64) {
        int k = fidx[rcb * 64 + tid];
        kb[tid] = k;
        out[(size_t)IDX_OFF + (size_t)rcb * 64 + tid] = (float)k;
        atomicAdd(&counts[k], 1);
    }
    __syncthreads();

    // stage the 64 referenced emb rows: one wave-instr = one coalesced 1KB row.
    #pragma unroll 4
    for (int it = 0; it < 16; ++it) {
        const int flat = it * 256 + tid;       // 4096 float4
        const int row = flat >> 6, c4 = (flat & 63) << 2;
        float4 v = *(const float4*)(emb + (size_t)kb[row] * D_DIM + c4);
        L[row][c4 + 0] = v.x; L[row][c4 + 1] = v.y;
        L[row][c4 + 2] = v.z; L[row][c4 + 3] = v.w;
    }
    __syncthreads();

    const int j4 = (tid & 15) << 2;   // hw offset within the 64-chunk, float4
    const int dq = tid >> 4;          // 16 d-slices
    const size_t base = (size_t)b * 262144 + hw0 + j4;
    float ls = 0.f;
    #pragma unroll 4
    for (int d = dq; d < D_DIM; d += 16) {
        size_t off = base + ((size_t)d << 10);
        float4 x = *(const float4*)(z_e + off);
        float4 q;
        q.x = L[j4 + 0][d]; q.y = L[j4 + 1][d];
        q.z = L[j4 + 2][d]; q.w = L[j4 + 3][d];
        *(float4*)(out + off) = q;
        float d0 = q.x - x.x, d1 = q.y - x.y, d2 = q.z - x.z, d3 = q.w - x.w;
        ls += d0 * d0; ls += d1 * d1; ls += d2 * d2; ls += d3 * d3;
    }
    rs[tid] = ls;
    __syncthreads();
    for (int s = 128; s > 0; s >>= 1) {
        if (tid < s) rs[tid] += rs[tid + s];
        __syncthreads();
    }
    if (tid == 0) atomicAdd(loss_sum, rs[0]);
}

__global__ void finalize_kernel(const int* __restrict__ counts,
                                const float* __restrict__ loss_sum,
                                float* __restrict__ out) {
    __shared__ float rs[256];
    const int tid = threadIdx.x;
    float s = 0.f;
    for (int k = tid; k < K_CODES; k += 256) {
        float p = (float)counts[k] / 65536.0f;
        s += p * logf(p + 1e-10f);
    }
    rs[tid] = s;
    __syncthreads();
    for (int st = 128; st > 0; st >>= 1) {
        if (tid < st) rs[tid] += rs[tid + st];
        __syncthreads();
    }
    if (tid == 0) {
        out[N_ELEM]     = loss_sum[0] * 1.25f / 16777216.0f;
        out[N_ELEM + 1] = expf(-rs[0]);
    }
}

extern "C" void kernel_launch(void* const* d_in, const int* in_sizes, int n_in,
                              void* d_out, int out_size, void* d_ws, size_t ws_size,
                              hipStream_t stream) {
    const float* z_e = (const float*)d_in[0];
    const float* emb = (const float*)d_in[1];
    float* out = (float*)d_out;
    char*  ws  = (char*)d_ws;

    // big scratch inside d_out (overwritten by epilogue)
    unsigned short* A_hi = (unsigned short*)d_out;

    float*          enorm    = (float*)ws;
    float*          xnorm    = (float*)(ws + 4096);
    int*            fidx     = (int*)(ws + 266240);
    int*            counts   = (int*)(ws + 528384);
    float*          loss_sum = (float*)(ws + 532480);
    int*            amb_cnt  = (int*)(ws + 532484);
    int*            amb      = (int*)(ws + 532488);
    unsigned short* B_hi     = (unsigned short*)(ws + 794752);
    float*          embT     = (float*)(ws + 1319040);

    prep_kernel<<<2052, 256, 0, stream>>>(z_e, emb, A_hi, xnorm, enorm, B_hi, embT,
                                          counts, loss_sum, amb_cnt);
    dist2_kernel<<<512, 256, 0, stream>>>(A_hi, B_hi, enorm, fidx, amb, amb_cnt);
    rescue4_kernel<<<1024, 512, 0, stream>>>(z_e, embT, xnorm, enorm, amb, amb_cnt, fidx);
    epilogue_kernel<<<N_ROWS / 64, 256, 0, stream>>>(z_e, emb, fidx, out, counts, loss_sum);
    finalize_kernel<<<1, 256, 0, stream>>>(counts, loss_sum, out);
}